// Round 21
// baseline (3111.812 us; speedup 1.0000x reference)
//
#include <hip/hip_runtime.h>
#include <hip/hip_bf16.h>
#include <hip/hip_cooperative_groups.h>
#include <math.h>
#include <type_traits>

namespace cg = cooperative_groups;

#define HIDDEN 256
#define SEQ 2048
#define BATCH 64
#define INSZ 128
#define OUTSZ 64
#define DTC 0.05f
#define CCH 32           // pipeline chunks
#define CHS (SEQ / CCH)  // 64 steps per chunk
#define TBLK (CHS / 32)  // 2 gemm row-blocks per batch-chunk

typedef _Float16 f16x8 __attribute__((ext_vector_type(8)));
typedef float f32x4 __attribute__((ext_vector_type(4)));

// ---------------- K0: complexity net + alphas ----------------
__global__ __launch_bounds__(1024) void prep_kernel(
    const float* __restrict__ x, const float* __restrict__ cw1, const float* __restrict__ cb1,
    const float* __restrict__ cw2, const float* __restrict__ cb2,
    const float* __restrict__ tau_b, const float* __restrict__ tmw, const float* __restrict__ tmb,
    float* __restrict__ alphas)
{
    __shared__ float p_lds[8][128];
    __shared__ float xm[128];
    __shared__ float t1[64];
    int b = blockIdx.x;
    int tid = threadIdx.x;
    int c = tid & 127, sh = tid >> 7;
    const float* xb = x + (size_t)b * SEQ * INSZ;
    float s = 0.f;
    for (int t = sh * 256; t < (sh + 1) * 256; ++t) s += xb[(size_t)t * INSZ + c];
    p_lds[sh][c] = s;
    __syncthreads();
    if (tid < 128) {
        float m = 0.f;
        #pragma unroll
        for (int i = 0; i < 8; ++i) m += p_lds[i][tid];
        xm[tid] = m / (float)SEQ;
    }
    __syncthreads();
    if (tid < 64) {
        float acc = cb1[tid];
        for (int k = 0; k < 128; ++k) acc += xm[k] * cw1[tid * 128 + k];
        t1[tid] = fmaxf(acc, 0.f);
    }
    __syncthreads();
    if (tid == 0) {
        float acc = cb2[0];
        for (int k = 0; k < 64; ++k) acc += t1[k] * cw2[k];
        float comp = 1.f / (1.f + expf(-acc));
        for (int i = 0; i < 3; ++i) {
            float lg[4], mx = -1e30f;
            for (int j = 0; j < 4; ++j) { lg[j] = comp * tmw[i * 4 + j] + tmb[i * 4 + j]; mx = fmaxf(mx, lg[j]); }
            float den = 0.f;
            for (int j = 0; j < 4; ++j) { lg[j] = expf(lg[j] - mx); den += lg[j]; }
            float mt = 0.f;
            for (int j = 0; j < 4; ++j) mt += tau_b[i * 4 + j] * (lg[j] / den);
            alphas[i * 64 + b] = expf(-DTC / mt);
        }
    }
}

// ---------------- Wf = W_in0 @ pw  (256x128), bf = W_in0 @ pb + bias0 ----------------
__global__ __launch_bounds__(128) void wf_kernel(
    const float* __restrict__ W_in0, const float* __restrict__ pw,
    const float* __restrict__ pb, const float* __restrict__ bias0,
    float* __restrict__ Wf, float* __restrict__ bf)
{
    __shared__ float wrow[256];
    int j = blockIdx.x, k = threadIdx.x;
    for (int m = k; m < 256; m += 128) wrow[m] = W_in0[j * 256 + m];
    __syncthreads();
    float s = 0.f;
    for (int m = 0; m < 256; ++m) s = fmaf(wrow[m], pw[m * 128 + k], s);
    Wf[j * 128 + k] = s;
    if (k == 0) {
        float sb = bias0[j];
        for (int m = 0; m < 256; ++m) sb = fmaf(wrow[m], pb[m], sb);
        bf[j] = sb;
    }
}

__device__ __forceinline__ unsigned pkrtz(float a, float b) {
    return __builtin_bit_cast(unsigned, __builtin_amdgcn_cvt_pkrtz(a, b));
}

// ---------------- pack a 256x256 f32 matrix into per-lane f16 fragments ----------------
__global__ __launch_bounds__(64) void wpack_kernel(
    const float* __restrict__ W, _Float16* __restrict__ P)
{
    int blk = blockIdx.x;            // (wave*4+mt)*8+kt, 128 blocks
    int wave = blk >> 5, mt = (blk >> 3) & 3, kt = blk & 7;
    int lane = threadIdx.x;
    int row = wave * 64 + mt * 16 + (lane & 15);
    int kcol = kt * 32 + (lane >> 4) * 8;
    const float4* s = (const float4*)(W + (size_t)row * 256 + kcol);
    float4 a = s[0], b = s[1];
    uint4 u = { pkrtz(a.x, a.y), pkrtz(a.z, a.w), pkrtz(b.x, b.y), pkrtz(b.z, b.w) };
    *(uint4*)((char*)P + (size_t)blk * 1024 + lane * 16) = u;
}

__device__ __forceinline__ float fast_tanh(float x) {
    float ex = __expf(2.f * x);
    float r = __builtin_amdgcn_rcpf(ex + 1.f);
    return 1.f - 2.f * r;
}

__device__ __forceinline__ void barrier_lds_only() {
    asm volatile("s_waitcnt lgkmcnt(0)\n\ts_barrier" ::: "memory");
}

// ---------------- MFMA GEMM for ext0 (full seq; r17-verified) ----------------
__global__ __launch_bounds__(256, 2) void gemm0_kernel(
    const float* __restrict__ Asrc, const float* __restrict__ W,
    const float* __restrict__ bias, float* __restrict__ C)
{
    constexpr int KD = 128, KT = 4, ROWB = 256;
    __shared__ alignas(16) char alds[32 * ROWB];
    const int tid = threadIdx.x;
    const int wave = tid >> 6, lane = tid & 63;
    const int bl = lane & 15, q = lane >> 4;
    const int m0 = blockIdx.x * 32;

    f16x8 bfrag[4][KT];
    float bv[4];
    #pragma unroll
    for (int nt = 0; nt < 4; ++nt) {
        int n = wave * 64 + nt * 16 + bl;
        const float* wr = W + (size_t)n * KD;
        #pragma unroll
        for (int kt = 0; kt < KT; ++kt) {
            const float4* wp = (const float4*)(wr + kt * 32 + q * 8);
            float4 u0 = wp[0], u1 = wp[1];
            uint4 u = { pkrtz(u0.x, u0.y), pkrtz(u0.z, u0.w),
                        pkrtz(u1.x, u1.y), pkrtz(u1.z, u1.w) };
            bfrag[nt][kt] = __builtin_bit_cast(f16x8, u);
        }
        bv[nt] = bias[n];
    }
    #pragma unroll
    for (int it = 0; it < 2; ++it) {
        int idx = tid + it * 256;
        int row = idx >> 4, chunk = idx & 15;
        const float4* sp = (const float4*)(Asrc + (size_t)(m0 + row) * KD + chunk * 8);
        float4 f0 = sp[0], f1 = sp[1];
        uint4 u = { pkrtz(f0.x, f0.y), pkrtz(f0.z, f0.w),
                    pkrtz(f1.x, f1.y), pkrtz(f1.z, f1.w) };
        *(uint4*)(alds + row * ROWB + ((chunk * 16) ^ ((row & 7) << 4))) = u;
    }
    __syncthreads();

    f32x4 acc[2][4];
    #pragma unroll
    for (int mt = 0; mt < 2; ++mt)
        #pragma unroll
        for (int nt = 0; nt < 4; ++nt) acc[mt][nt] = (f32x4){0.f, 0.f, 0.f, 0.f};
    #pragma unroll
    for (int kt = 0; kt < KT; ++kt) {
        int inner = kt * 64 + q * 16;
        f16x8 a0 = __builtin_bit_cast(f16x8,
            *(const uint4*)(alds + (0 * 16 + bl) * ROWB + (inner ^ ((bl & 7) << 4))));
        f16x8 a1 = __builtin_bit_cast(f16x8,
            *(const uint4*)(alds + (1 * 16 + bl) * ROWB + (inner ^ ((bl & 7) << 4))));
        #pragma unroll
        for (int nt = 0; nt < 4; ++nt) {
            acc[0][nt] = __builtin_amdgcn_mfma_f32_16x16x32_f16(a0, bfrag[nt][kt], acc[0][nt], 0, 0, 0);
            acc[1][nt] = __builtin_amdgcn_mfma_f32_16x16x32_f16(a1, bfrag[nt][kt], acc[1][nt], 0, 0, 0);
        }
    }
    #pragma unroll
    for (int mt = 0; mt < 2; ++mt)
        #pragma unroll
        for (int nt = 0; nt < 4; ++nt) {
            int col = wave * 64 + nt * 16 + bl;
            #pragma unroll
            for (int r = 0; r < 4; ++r)
                C[(size_t)(m0 + mt * 16 + q * 4 + r) * 256 + col] = acc[mt][nt][r] + bv[nt];
        }
}

// ---------------- persistent pipeline kernel: 256 blocks (1/CU), grid.sync between stages ----------------
// blocks [0,192): scan role (layer = blk>>6, batch = blk&63) — weights + h in regs for ALL stages
// blocks [192,256): gemm role (which = (blk-192)>>5, gl = (blk-192)&31) — 2 batches x 2 tiles per stage
__global__ __launch_bounds__(256, 1) void persist_kernel(
    float* __restrict__ buf,
    const _Float16* __restrict__ wpk,   // [5][65536]: Wrec0,Wrec1,Wrec2,Win1,Win2
    const float* __restrict__ bias,
    const float* __restrict__ alphas,
    float* __restrict__ h_carry)        // only [2] slot written (final layer)
{
    cg::grid_group grid = cg::this_grid();
    __shared__ alignas(16) char smem[16384];
    const int blk = blockIdx.x;
    const int tid = threadIdx.x;

    if (blk < 192) {
        // ================= SCAN ROLE =================
        const int layer = blk >> 6, b = blk & 63;
        const int wave = tid >> 6, lane = tid & 63;
        const int bl = lane & 15, q = lane >> 4;
        const int mt_own = bl >> 2, r_own = bl & 3;
        const int m = wave * 64 + mt_own * 16 + q * 4 + r_own;
        const _Float16* Wp = wpk + (size_t)layer * 65536;
        _Float16 (*hlds)[256] = (_Float16 (*)[256])smem;

        f16x8 afrag[4][8];
        #pragma unroll
        for (int mt = 0; mt < 4; ++mt)
            #pragma unroll
            for (int kt = 0; kt < 8; ++kt)
                afrag[mt][kt] = __builtin_bit_cast(f16x8,
                    *(const uint4*)((const char*)Wp + (size_t)(((wave * 4 + mt) * 8 + kt) * 64 + lane) * 16));

        const float alpha = alphas[layer * 64 + b], onema = 1.f - alpha;
        float* bb = buf + (size_t)b * SEQ * HIDDEN;
        const int write_all = (layer < 2);
        float h_reg = 0.f;                       // speculative zero init (register-resident carry)

        for (int s = 0; s < CCH + 4; ++s) {
            int c = s - 2 * layer;
            if (c >= 0 && c < CCH) {
                const int t0 = c * CHS, tend = t0 + CHS;
                hlds[0][m] = (_Float16)h_reg;
                float e_cur = bb[(size_t)t0 * HIDDEN + m];
                float e_n1  = bb[(size_t)(t0 + 1) * HIDDEN + m];
                __syncthreads();

                auto step = [&](auto CB, int t) {
                    constexpr int CUR = decltype(CB)::value;
                    const char* rb = (const char*)&hlds[CUR][0];
                    uint4 bq0 = *(const uint4*)(rb + q * 16);
                    uint4 bq1 = *(const uint4*)(rb + 64 + q * 16);
                    uint4 bq2 = *(const uint4*)(rb + 128 + q * 16);
                    uint4 bq3 = *(const uint4*)(rb + 192 + q * 16);
                    uint4 bq4 = *(const uint4*)(rb + 256 + q * 16);
                    uint4 bq5 = *(const uint4*)(rb + 320 + q * 16);
                    uint4 bq6 = *(const uint4*)(rb + 384 + q * 16);
                    uint4 bq7 = *(const uint4*)(rb + 448 + q * 16);
                    float e_n2 = 0.f;
                    if (t + 2 < tend) e_n2 = bb[(size_t)(t + 2) * HIDDEN + m];

                    f32x4 a0 = {0.f,0.f,0.f,0.f}, a1 = {0.f,0.f,0.f,0.f};
                    f32x4 a2 = {0.f,0.f,0.f,0.f}, a3 = {0.f,0.f,0.f,0.f};
                    #define MSTEP(BQ, KT) { f16x8 bf = __builtin_bit_cast(f16x8, BQ);                  \
                        a0 = __builtin_amdgcn_mfma_f32_16x16x32_f16(afrag[0][KT], bf, a0, 0, 0, 0);    \
                        a1 = __builtin_amdgcn_mfma_f32_16x16x32_f16(afrag[1][KT], bf, a1, 0, 0, 0);    \
                        a2 = __builtin_amdgcn_mfma_f32_16x16x32_f16(afrag[2][KT], bf, a2, 0, 0, 0);    \
                        a3 = __builtin_amdgcn_mfma_f32_16x16x32_f16(afrag[3][KT], bf, a3, 0, 0, 0); }
                    MSTEP(bq0, 0) MSTEP(bq1, 1) MSTEP(bq2, 2) MSTEP(bq3, 3)
                    MSTEP(bq4, 4) MSTEP(bq5, 5) MSTEP(bq6, 6) MSTEP(bq7, 7)
                    #undef MSTEP

                    f32x4 am = (mt_own == 0) ? a0 : (mt_own == 1) ? a1 : (mt_own == 2) ? a2 : a3;
                    float sv = (r_own == 0) ? am[0] : (r_own == 1) ? am[1] : (r_own == 2) ? am[2] : am[3];

                    float act = fast_tanh(sv + e_cur);
                    h_reg = alpha * h_reg + onema * act;
                    hlds[CUR ^ 1][m] = (_Float16)h_reg;
                    if (write_all)
                        *((_Float16*)(bb + (size_t)t * HIDDEN) + m) = (_Float16)h_reg;
                    barrier_lds_only();
                    e_cur = e_n1;
                    e_n1 = e_n2;
                };

                for (int t = t0; t < tend; t += 2) {
                    step(std::integral_constant<int, 0>{}, t);
                    step(std::integral_constant<int, 1>{}, t + 1);
                }
            }
            __threadfence();
            grid.sync();
        }
        if (layer == 2) h_carry[2 * 16384 + b * 256 + m] = h_reg;
    } else {
        // ================= GEMM ROLE =================
        constexpr int KT = 8, ROWB = 512;
        char* alds = smem;   // 32 rows * 512B = 16 KB
        const int g = blk - 192;
        const int which = g >> 5, gl = g & 31;
        const int wave = tid >> 6, lane = tid & 63;
        const int bl = lane & 15, q = lane >> 4;
        const _Float16* Wp = wpk + (size_t)(3 + which) * 65536;
        const float* bias_l = bias + (which + 1) * 256;

        f16x8 bfrag[4][KT];
        float bv[4];
        #pragma unroll
        for (int nt = 0; nt < 4; ++nt) {
            #pragma unroll
            for (int kt = 0; kt < KT; ++kt)
                bfrag[nt][kt] = __builtin_bit_cast(f16x8,
                    *(const uint4*)((const char*)Wp + (size_t)(((wave * 4 + nt) * 8 + kt) * 64 + lane) * 16));
            bv[nt] = bias_l[wave * 64 + nt * 16 + bl];
        }

        for (int s = 0; s < CCH + 4; ++s) {
            int c = s - 1 - 2 * which;
            if (c >= 0 && c < CCH) {
                for (int u = 0; u < 2 * TBLK; ++u) {
                    int b = 2 * gl + (u >> 1);
                    int half = u & 1;
                    size_t m0 = (size_t)b * SEQ + (size_t)c * CHS + (size_t)half * 32;

                    __syncthreads();
                    #pragma unroll
                    for (int it = 0; it < 4; ++it) {
                        int idx = tid + it * 256;
                        int row = idx >> 5, chunk = idx & 31;
                        uint4 uu = *(const uint4*)((const char*)buf + (m0 + row) * 1024 + chunk * 16);
                        *(uint4*)(alds + row * ROWB + ((chunk * 16) ^ ((row & 7) << 4))) = uu;
                    }
                    __syncthreads();

                    f32x4 acc[2][4];
                    #pragma unroll
                    for (int mt = 0; mt < 2; ++mt)
                        #pragma unroll
                        for (int nt = 0; nt < 4; ++nt) acc[mt][nt] = (f32x4){0.f, 0.f, 0.f, 0.f};
                    #pragma unroll
                    for (int kt = 0; kt < KT; ++kt) {
                        int inner = kt * 64 + q * 16;
                        f16x8 a0 = __builtin_bit_cast(f16x8,
                            *(const uint4*)(alds + (0 * 16 + bl) * ROWB + (inner ^ ((bl & 7) << 4))));
                        f16x8 a1 = __builtin_bit_cast(f16x8,
                            *(const uint4*)(alds + (1 * 16 + bl) * ROWB + (inner ^ ((bl & 7) << 4))));
                        #pragma unroll
                        for (int nt = 0; nt < 4; ++nt) {
                            acc[0][nt] = __builtin_amdgcn_mfma_f32_16x16x32_f16(a0, bfrag[nt][kt], acc[0][nt], 0, 0, 0);
                            acc[1][nt] = __builtin_amdgcn_mfma_f32_16x16x32_f16(a1, bfrag[nt][kt], acc[1][nt], 0, 0, 0);
                        }
                    }
                    #pragma unroll
                    for (int mt = 0; mt < 2; ++mt)
                        #pragma unroll
                        for (int nt = 0; nt < 4; ++nt) {
                            int col = wave * 64 + nt * 16 + bl;
                            #pragma unroll
                            for (int r = 0; r < 4; ++r)
                                buf[(m0 + mt * 16 + q * 4 + r) * 256 + col] = acc[mt][nt][r] + bv[nt];
                        }
                }
            }
            __threadfence();
            grid.sync();
        }
    }
}

// ---------------- final projection from h_carry[2] ----------------
__global__ __launch_bounds__(256) void outproj_kernel(
    const float* __restrict__ h_carry, const float* __restrict__ ow, const float* __restrict__ ob,
    float* __restrict__ out)
{
    __shared__ float h_l[256];
    __shared__ float p_lds[4][64];
    int b = blockIdx.x;
    int tid = threadIdx.x;
    h_l[tid] = h_carry[b * 256 + tid];
    __syncthreads();
    int o = tid & 63, qq = tid >> 6;
    float s = 0.f;
    const float4* wp = (const float4*)(ow + o * 256 + qq * 64);
    const float4* hp = (const float4*)(h_l + qq * 64);
    #pragma unroll
    for (int m = 0; m < 16; ++m) {
        float4 wv = wp[m]; float4 hv = hp[m];
        s = fmaf(wv.x, hv.x, s); s = fmaf(wv.y, hv.y, s);
        s = fmaf(wv.z, hv.z, s); s = fmaf(wv.w, hv.w, s);
    }
    p_lds[qq][o] = s;
    __syncthreads();
    if (tid < 64)
        out[b * 64 + tid] = p_lds[0][tid] + p_lds[1][tid] + p_lds[2][tid] + p_lds[3][tid] + ob[tid];
}

extern "C" void kernel_launch(void* const* d_in, const int* in_sizes, int n_in,
                              void* d_out, int out_size, void* d_ws, size_t ws_size,
                              hipStream_t stream)
{
    const float* x     = (const float*)d_in[0];
    const float* cw1   = (const float*)d_in[1];
    const float* cb1   = (const float*)d_in[2];
    const float* cw2   = (const float*)d_in[3];
    const float* cb2   = (const float*)d_in[4];
    const float* pw    = (const float*)d_in[5];
    const float* pb    = (const float*)d_in[6];
    const float* W_rec = (const float*)d_in[7];
    const float* W_in  = (const float*)d_in[8];
    const float* bias  = (const float*)d_in[9];
    const float* tau_b = (const float*)d_in[10];
    const float* tmw   = (const float*)d_in[11];
    const float* tmb   = (const float*)d_in[12];
    const float* ow    = (const float*)d_in[13];
    const float* ob    = (const float*)d_in[14];
    float* out = (float*)d_out;

    char* ws = (char*)d_ws;
    float*     alphas  = (float*)ws;                   // 192 f
    float*     h_carry = (float*)(ws + 1024);          // [3][64][256] f (only slot 2 used)
    float*     bf      = (float*)(ws + 197632);        // 256 f
    float*     Wf      = (float*)(ws + 198656);        // 256*128 f
    _Float16*  wpk     = (_Float16*)(ws + 329728);     // [5][65536] f16
    float*     buf     = (float*)(ws + 1048576);       // [64][2048][256] f32 = 134.2MB

    const int MROWS = BATCH * SEQ;      // 131072

    prep_kernel<<<64, 1024, 0, stream>>>(x, cw1, cb1, cw2, cb2, tau_b, tmw, tmb, alphas);
    wf_kernel<<<256, 128, 0, stream>>>(W_in, pw, pb, bias, Wf, bf);

    wpack_kernel<<<128, 64, 0, stream>>>(W_rec,          wpk);
    wpack_kernel<<<128, 64, 0, stream>>>(W_rec + 65536,  wpk + 65536);
    wpack_kernel<<<128, 64, 0, stream>>>(W_rec + 131072, wpk + 2 * 65536);
    wpack_kernel<<<128, 64, 0, stream>>>(W_in + 65536,   wpk + 3 * 65536);
    wpack_kernel<<<128, 64, 0, stream>>>(W_in + 131072,  wpk + 4 * 65536);

    // ext0 = x @ Wf.T + bf (input projection + W_in0 fused), full sequence
    gemm0_kernel<<<MROWS / 32, 256, 0, stream>>>(x, Wf, bf, buf);

    // persistent speculative pipeline: one cooperative kernel, grid.sync between stages
    {
        float* buf_p = buf;
        const _Float16* wpk_p = wpk;
        const float* bias_p = bias;
        const float* alphas_p = alphas;
        float* hc_p = h_carry;
        void* kargs[] = { &buf_p, &wpk_p, &bias_p, &alphas_p, &hc_p };
        hipLaunchCooperativeKernel((const void*)persist_kernel, dim3(256), dim3(256),
                                   kargs, 0, stream);
    }

    outproj_kernel<<<64, 256, 0, stream>>>(h_carry + 2 * 16384, ow, ob, out);
}

// Round 22
// 2208.790 us; speedup vs baseline: 1.4088x; 1.4088x over previous
//
#include <hip/hip_runtime.h>
#include <hip/hip_bf16.h>
#include <math.h>
#include <type_traits>

#define HIDDEN 256
#define SEQ 2048
#define BATCH 64
#define INSZ 128
#define OUTSZ 64
#define DTC 0.05f
#define CCH 32           // pipeline chunks
#define CHS (SEQ / CCH)  // 64 steps per chunk

typedef _Float16 f16x8 __attribute__((ext_vector_type(8)));
typedef float f32x4 __attribute__((ext_vector_type(4)));

// ---------------- K0: complexity net + alphas + zero h_carry ----------------
__global__ __launch_bounds__(1024) void prep_kernel(
    const float* __restrict__ x, const float* __restrict__ cw1, const float* __restrict__ cb1,
    const float* __restrict__ cw2, const float* __restrict__ cb2,
    const float* __restrict__ tau_b, const float* __restrict__ tmw, const float* __restrict__ tmb,
    float* __restrict__ alphas, float* __restrict__ h_carry)
{
    __shared__ float p_lds[8][128];
    __shared__ float xm[128];
    __shared__ float t1[64];
    int b = blockIdx.x;
    int tid = threadIdx.x;
    if (tid < 256) {
        h_carry[0 * 16384 + b * 256 + tid] = 0.f;
        h_carry[1 * 16384 + b * 256 + tid] = 0.f;
        h_carry[2 * 16384 + b * 256 + tid] = 0.f;
    }
    int c = tid & 127, sh = tid >> 7;
    const float* xb = x + (size_t)b * SEQ * INSZ;
    float s = 0.f;
    for (int t = sh * 256; t < (sh + 1) * 256; ++t) s += xb[(size_t)t * INSZ + c];
    p_lds[sh][c] = s;
    __syncthreads();
    if (tid < 128) {
        float m = 0.f;
        #pragma unroll
        for (int i = 0; i < 8; ++i) m += p_lds[i][tid];
        xm[tid] = m / (float)SEQ;
    }
    __syncthreads();
    if (tid < 64) {
        float acc = cb1[tid];
        for (int k = 0; k < 128; ++k) acc += xm[k] * cw1[tid * 128 + k];
        t1[tid] = fmaxf(acc, 0.f);
    }
    __syncthreads();
    if (tid == 0) {
        float acc = cb2[0];
        for (int k = 0; k < 64; ++k) acc += t1[k] * cw2[k];
        float comp = 1.f / (1.f + expf(-acc));
        for (int i = 0; i < 3; ++i) {
            float lg[4], mx = -1e30f;
            for (int j = 0; j < 4; ++j) { lg[j] = comp * tmw[i * 4 + j] + tmb[i * 4 + j]; mx = fmaxf(mx, lg[j]); }
            float den = 0.f;
            for (int j = 0; j < 4; ++j) { lg[j] = expf(lg[j] - mx); den += lg[j]; }
            float mt = 0.f;
            for (int j = 0; j < 4; ++j) mt += tau_b[i * 4 + j] * (lg[j] / den);
            alphas[i * 64 + b] = expf(-DTC / mt);
        }
    }
}

// ---------------- Wf = W_in0 @ pw  (256x128), bf = W_in0 @ pb + bias0 ----------------
__global__ __launch_bounds__(128) void wf_kernel(
    const float* __restrict__ W_in0, const float* __restrict__ pw,
    const float* __restrict__ pb, const float* __restrict__ bias0,
    float* __restrict__ Wf, float* __restrict__ bf)
{
    __shared__ float wrow[256];
    int j = blockIdx.x, k = threadIdx.x;
    for (int m = k; m < 256; m += 128) wrow[m] = W_in0[j * 256 + m];
    __syncthreads();
    float s = 0.f;
    for (int m = 0; m < 256; ++m) s = fmaf(wrow[m], pw[m * 128 + k], s);
    Wf[j * 128 + k] = s;
    if (k == 0) {
        float sb = bias0[j];
        for (int m = 0; m < 256; ++m) sb = fmaf(wrow[m], pb[m], sb);
        bf[j] = sb;
    }
}

__device__ __forceinline__ unsigned pkrtz(float a, float b) {
    return __builtin_bit_cast(unsigned, __builtin_amdgcn_cvt_pkrtz(a, b));
}

// ---------------- pack a 256x256 f32 matrix into per-lane f16 fragments ----------------
__global__ __launch_bounds__(64) void wpack_kernel(
    const float* __restrict__ W, _Float16* __restrict__ P)
{
    int blk = blockIdx.x;            // (wave*4+mt)*8+kt, 128 blocks
    int wave = blk >> 5, mt = (blk >> 3) & 3, kt = blk & 7;
    int lane = threadIdx.x;
    int row = wave * 64 + mt * 16 + (lane & 15);
    int kcol = kt * 32 + (lane >> 4) * 8;
    const float4* s = (const float4*)(W + (size_t)row * 256 + kcol);
    float4 a = s[0], b = s[1];
    uint4 u = { pkrtz(a.x, a.y), pkrtz(a.z, a.w), pkrtz(b.x, b.y), pkrtz(b.z, b.w) };
    *(uint4*)((char*)P + (size_t)blk * 1024 + lane * 16) = u;
}

__device__ __forceinline__ float fast_tanh(float x) {
    float ex = __expf(2.f * x);
    float r = __builtin_amdgcn_rcpf(ex + 1.f);
    return 1.f - 2.f * r;
}

__device__ __forceinline__ void barrier_lds_only() {
    asm volatile("s_waitcnt lgkmcnt(0)\n\ts_barrier" ::: "memory");
}

// ---------------- fused scan chunk: h recurrence + deferred ext_next = Win_next @ h ----------------
// At step t the B fragments hold h[t-1]; E = Win·h[t-1] is computed on idle MFMA slots and
// stored to ext_next[t-1] (in place over consumed ext). Chunk-tail epilogue emits ext_next[tend-1].
template<bool FUSE>
__device__ __forceinline__ void scan_chunk_f(
    char* smem, float* buf,
    const _Float16* __restrict__ Wp,   // Wrec fragments
    const _Float16* __restrict__ Wn,   // Win_next fragments (FUSE only)
    const float* __restrict__ bias_n,  // bias_next (FUSE only)
    const float* __restrict__ alphas, float* __restrict__ h_carry,
    int b, int c)
{
    _Float16 (*hlds)[256] = (_Float16 (*)[256])smem;   // [2][256]
    const int tid = threadIdx.x;
    const int wave = tid >> 6, lane = tid & 63;
    const int bl = lane & 15, q = lane >> 4;
    const int mt_own = bl >> 2, r_own = bl & 3;
    const int m = wave * 64 + mt_own * 16 + q * 4 + r_own;

    f16x8 afrag[4][8];
    #pragma unroll
    for (int mt = 0; mt < 4; ++mt)
        #pragma unroll
        for (int kt = 0; kt < 8; ++kt)
            afrag[mt][kt] = __builtin_bit_cast(f16x8,
                *(const uint4*)((const char*)Wp + (size_t)(((wave * 4 + mt) * 8 + kt) * 64 + lane) * 16));
    f16x8 wfrag[4][8];
    if (FUSE) {
        #pragma unroll
        for (int mt = 0; mt < 4; ++mt)
            #pragma unroll
            for (int kt = 0; kt < 8; ++kt)
                wfrag[mt][kt] = __builtin_bit_cast(f16x8,
                    *(const uint4*)((const char*)Wn + (size_t)(((wave * 4 + mt) * 8 + kt) * 64 + lane) * 16));
    }
    const float bn = FUSE ? bias_n[m] : 0.f;

    const float alpha = alphas[b], onema = 1.f - alpha;
    float* bb = buf + (size_t)b * SEQ * HIDDEN;
    const int t0 = c * CHS, tend = t0 + CHS;

    float h_reg = h_carry[b * 256 + m];
    hlds[0][m] = (_Float16)h_reg;
    float e_cur = bb[(size_t)t0 * HIDDEN + m];
    float e_n1  = bb[(size_t)(t0 + 1) * HIDDEN + m];
    __syncthreads();

    auto step = [&](auto CB, int t) {
        constexpr int CUR = decltype(CB)::value;
        const char* rb = (const char*)&hlds[CUR][0];
        uint4 bq0 = *(const uint4*)(rb + q * 16);
        uint4 bq1 = *(const uint4*)(rb + 64 + q * 16);
        uint4 bq2 = *(const uint4*)(rb + 128 + q * 16);
        uint4 bq3 = *(const uint4*)(rb + 192 + q * 16);
        uint4 bq4 = *(const uint4*)(rb + 256 + q * 16);
        uint4 bq5 = *(const uint4*)(rb + 320 + q * 16);
        uint4 bq6 = *(const uint4*)(rb + 384 + q * 16);
        uint4 bq7 = *(const uint4*)(rb + 448 + q * 16);
        float e_n2 = 0.f;
        if (t + 2 < tend) e_n2 = bb[(size_t)(t + 2) * HIDDEN + m];

        f32x4 a0 = {0.f,0.f,0.f,0.f}, a1 = {0.f,0.f,0.f,0.f};
        f32x4 a2 = {0.f,0.f,0.f,0.f}, a3 = {0.f,0.f,0.f,0.f};
        #define MSTEP(FR, BQ, KT, X0, X1, X2, X3) { f16x8 bf_ = __builtin_bit_cast(f16x8, BQ); \
            X0 = __builtin_amdgcn_mfma_f32_16x16x32_f16(FR[0][KT], bf_, X0, 0, 0, 0);          \
            X1 = __builtin_amdgcn_mfma_f32_16x16x32_f16(FR[1][KT], bf_, X1, 0, 0, 0);          \
            X2 = __builtin_amdgcn_mfma_f32_16x16x32_f16(FR[2][KT], bf_, X2, 0, 0, 0);          \
            X3 = __builtin_amdgcn_mfma_f32_16x16x32_f16(FR[3][KT], bf_, X3, 0, 0, 0); }
        MSTEP(afrag, bq0, 0, a0, a1, a2, a3) MSTEP(afrag, bq1, 1, a0, a1, a2, a3)
        MSTEP(afrag, bq2, 2, a0, a1, a2, a3) MSTEP(afrag, bq3, 3, a0, a1, a2, a3)
        MSTEP(afrag, bq4, 4, a0, a1, a2, a3) MSTEP(afrag, bq5, 5, a0, a1, a2, a3)
        MSTEP(afrag, bq6, 6, a0, a1, a2, a3) MSTEP(afrag, bq7, 7, a0, a1, a2, a3)

        if (FUSE) {
            // E = Win_next · h[t-1] — off the critical path, idle MFMA slots
            f32x4 e0 = {0.f,0.f,0.f,0.f}, e1 = {0.f,0.f,0.f,0.f};
            f32x4 e2 = {0.f,0.f,0.f,0.f}, e3 = {0.f,0.f,0.f,0.f};
            MSTEP(wfrag, bq0, 0, e0, e1, e2, e3) MSTEP(wfrag, bq1, 1, e0, e1, e2, e3)
            MSTEP(wfrag, bq2, 2, e0, e1, e2, e3) MSTEP(wfrag, bq3, 3, e0, e1, e2, e3)
            MSTEP(wfrag, bq4, 4, e0, e1, e2, e3) MSTEP(wfrag, bq5, 5, e0, e1, e2, e3)
            MSTEP(wfrag, bq6, 6, e0, e1, e2, e3) MSTEP(wfrag, bq7, 7, e0, e1, e2, e3)
            if (t > t0) {
                f32x4 em = (mt_own == 0) ? e0 : (mt_own == 1) ? e1 : (mt_own == 2) ? e2 : e3;
                float ev = (r_own == 0) ? em[0] : (r_own == 1) ? em[1] : (r_own == 2) ? em[2] : em[3];
                bb[(size_t)(t - 1) * HIDDEN + m] = ev + bn;   // ext_next[t-1], in place
            }
        }

        f32x4 am = (mt_own == 0) ? a0 : (mt_own == 1) ? a1 : (mt_own == 2) ? a2 : a3;
        float sv = (r_own == 0) ? am[0] : (r_own == 1) ? am[1] : (r_own == 2) ? am[2] : am[3];

        float act = fast_tanh(sv + e_cur);
        h_reg = alpha * h_reg + onema * act;
        hlds[CUR ^ 1][m] = (_Float16)h_reg;
        barrier_lds_only();
        e_cur = e_n1;
        e_n1 = e_n2;
    };

    for (int t = t0; t < tend; t += 2) {
        step(std::integral_constant<int, 0>{}, t);
        step(std::integral_constant<int, 1>{}, t + 1);
    }

    if (FUSE) {
        // epilogue: ext_next[tend-1] from final h (in hlds[0] after even step count)
        const char* rb = (const char*)&hlds[0][0];
        uint4 bq0 = *(const uint4*)(rb + q * 16);
        uint4 bq1 = *(const uint4*)(rb + 64 + q * 16);
        uint4 bq2 = *(const uint4*)(rb + 128 + q * 16);
        uint4 bq3 = *(const uint4*)(rb + 192 + q * 16);
        uint4 bq4 = *(const uint4*)(rb + 256 + q * 16);
        uint4 bq5 = *(const uint4*)(rb + 320 + q * 16);
        uint4 bq6 = *(const uint4*)(rb + 384 + q * 16);
        uint4 bq7 = *(const uint4*)(rb + 448 + q * 16);
        f32x4 e0 = {0.f,0.f,0.f,0.f}, e1 = {0.f,0.f,0.f,0.f};
        f32x4 e2 = {0.f,0.f,0.f,0.f}, e3 = {0.f,0.f,0.f,0.f};
        MSTEP(wfrag, bq0, 0, e0, e1, e2, e3) MSTEP(wfrag, bq1, 1, e0, e1, e2, e3)
        MSTEP(wfrag, bq2, 2, e0, e1, e2, e3) MSTEP(wfrag, bq3, 3, e0, e1, e2, e3)
        MSTEP(wfrag, bq4, 4, e0, e1, e2, e3) MSTEP(wfrag, bq5, 5, e0, e1, e2, e3)
        MSTEP(wfrag, bq6, 6, e0, e1, e2, e3) MSTEP(wfrag, bq7, 7, e0, e1, e2, e3)
        f32x4 em = (mt_own == 0) ? e0 : (mt_own == 1) ? e1 : (mt_own == 2) ? e2 : e3;
        float ev = (r_own == 0) ? em[0] : (r_own == 1) ? em[1] : (r_own == 2) ? em[2] : em[3];
        bb[(size_t)(tend - 1) * HIDDEN + m] = ev + bn;
        #undef MSTEP
    }
    h_carry[b * 256 + m] = h_reg;
}

// ---------------- gemm0 chunk: ext0 = x @ Wf.T + bf for one (batch, chunk) = 64 rows ----------------
__device__ __forceinline__ void gemm0_chunk(
    char* smem, const float* __restrict__ x, const float* __restrict__ Wf,
    const float* __restrict__ bf, float* __restrict__ buf, int gl, int c)
{
    constexpr int KD = 128, KT = 4, ROWB = 256;
    char* alds = smem;   // 32 rows * 256B = 8 KB
    const int tid = threadIdx.x;
    const int wave = tid >> 6, lane = tid & 63;
    const int bl = lane & 15, q = lane >> 4;

    f16x8 bfrag[4][KT];
    float bv[4];
    #pragma unroll
    for (int nt = 0; nt < 4; ++nt) {
        int n = wave * 64 + nt * 16 + bl;
        const float* wr = Wf + (size_t)n * KD;
        #pragma unroll
        for (int kt = 0; kt < KT; ++kt) {
            const float4* wp = (const float4*)(wr + kt * 32 + q * 8);
            float4 u0 = wp[0], u1 = wp[1];
            uint4 u = { pkrtz(u0.x, u0.y), pkrtz(u0.z, u0.w),
                        pkrtz(u1.x, u1.y), pkrtz(u1.z, u1.w) };
            bfrag[nt][kt] = __builtin_bit_cast(f16x8, u);
        }
        bv[nt] = bf[n];
    }

    for (int half = 0; half < 2; ++half) {
        size_t m0 = (size_t)gl * SEQ + (size_t)c * CHS + (size_t)half * 32;
        const float* Asrc = x + m0 * KD;

        __syncthreads();
        #pragma unroll
        for (int it = 0; it < 2; ++it) {
            int idx = tid + it * 256;
            int row = idx >> 4, chunk = idx & 15;
            const float4* sp = (const float4*)(Asrc + (size_t)row * KD + chunk * 8);
            float4 f0 = sp[0], f1 = sp[1];
            uint4 u = { pkrtz(f0.x, f0.y), pkrtz(f0.z, f0.w),
                        pkrtz(f1.x, f1.y), pkrtz(f1.z, f1.w) };
            *(uint4*)(alds + row * ROWB + ((chunk * 16) ^ ((row & 7) << 4))) = u;
        }
        __syncthreads();

        f32x4 acc[2][4];
        #pragma unroll
        for (int mt = 0; mt < 2; ++mt)
            #pragma unroll
            for (int nt = 0; nt < 4; ++nt) acc[mt][nt] = (f32x4){0.f, 0.f, 0.f, 0.f};
        #pragma unroll
        for (int kt = 0; kt < KT; ++kt) {
            int inner = kt * 64 + q * 16;
            f16x8 a0 = __builtin_bit_cast(f16x8,
                *(const uint4*)(alds + (0 * 16 + bl) * ROWB + (inner ^ ((bl & 7) << 4))));
            f16x8 a1 = __builtin_bit_cast(f16x8,
                *(const uint4*)(alds + (1 * 16 + bl) * ROWB + (inner ^ ((bl & 7) << 4))));
            #pragma unroll
            for (int nt = 0; nt < 4; ++nt) {
                acc[0][nt] = __builtin_amdgcn_mfma_f32_16x16x32_f16(a0, bfrag[nt][kt], acc[0][nt], 0, 0, 0);
                acc[1][nt] = __builtin_amdgcn_mfma_f32_16x16x32_f16(a1, bfrag[nt][kt], acc[1][nt], 0, 0, 0);
            }
        }
        #pragma unroll
        for (int mt = 0; mt < 2; ++mt)
            #pragma unroll
            for (int nt = 0; nt < 4; ++nt) {
                int col = wave * 64 + nt * 16 + bl;
                #pragma unroll
                for (int r = 0; r < 4; ++r)
                    buf[(m0 + mt * 16 + q * 4 + r) * 256 + col] = acc[mt][nt][r] + bv[nt];
            }
    }
}

// ---------------- stage megakernel: 256 blocks ----------------
// [0,64): scanL0(c=s-1) fused ext1; [64,128): scanL1(c=s-2) fused ext2;
// [128,192): scanL2(c=s-3); [192,256): gemm0(c=s). Deps ride launch order.
__global__ __launch_bounds__(256, 1) void stage_kernel(
    int stage, float* buf, const float* __restrict__ x,
    const _Float16* __restrict__ wpk,   // [5][65536]: Wrec0,Wrec1,Wrec2,Win1,Win2
    const float* __restrict__ Wf, const float* __restrict__ bf,
    const float* __restrict__ bias, const float* __restrict__ alphas,
    float* __restrict__ h_carry)
{
    __shared__ alignas(16) char smem[8192];
    int blk = blockIdx.x;
    if (blk < 192) {
        int layer = blk >> 6;
        int c = stage - 1 - layer;
        if (c < 0 || c >= CCH) return;
        int b = blk & 63;
        if (layer == 0)
            scan_chunk_f<true>(smem, buf, wpk, wpk + 3 * 65536, bias + 256,
                               alphas, h_carry, b, c);
        else if (layer == 1)
            scan_chunk_f<true>(smem, buf, wpk + 65536, wpk + 4 * 65536, bias + 512,
                               alphas + 64, h_carry + 16384, b, c);
        else
            scan_chunk_f<false>(smem, buf, wpk + 2 * 65536, nullptr, nullptr,
                                alphas + 128, h_carry + 2 * 16384, b, c);
    } else {
        int gl = blk - 192;
        int c = stage;
        if (c >= CCH) return;
        gemm0_chunk(smem, x, Wf, bf, buf, gl, c);
    }
}

// ---------------- final projection from h_carry[2] ----------------
__global__ __launch_bounds__(256) void outproj_kernel(
    const float* __restrict__ h_carry, const float* __restrict__ ow, const float* __restrict__ ob,
    float* __restrict__ out)
{
    __shared__ float h_l[256];
    __shared__ float p_lds[4][64];
    int b = blockIdx.x;
    int tid = threadIdx.x;
    h_l[tid] = h_carry[b * 256 + tid];
    __syncthreads();
    int o = tid & 63, qq = tid >> 6;
    float s = 0.f;
    const float4* wp = (const float4*)(ow + o * 256 + qq * 64);
    const float4* hp = (const float4*)(h_l + qq * 64);
    #pragma unroll
    for (int m = 0; m < 16; ++m) {
        float4 wv = wp[m]; float4 hv = hp[m];
        s = fmaf(wv.x, hv.x, s); s = fmaf(wv.y, hv.y, s);
        s = fmaf(wv.z, hv.z, s); s = fmaf(wv.w, hv.w, s);
    }
    p_lds[qq][o] = s;
    __syncthreads();
    if (tid < 64)
        out[b * 64 + tid] = p_lds[0][tid] + p_lds[1][tid] + p_lds[2][tid] + p_lds[3][tid] + ob[tid];
}

extern "C" void kernel_launch(void* const* d_in, const int* in_sizes, int n_in,
                              void* d_out, int out_size, void* d_ws, size_t ws_size,
                              hipStream_t stream)
{
    const float* x     = (const float*)d_in[0];
    const float* cw1   = (const float*)d_in[1];
    const float* cb1   = (const float*)d_in[2];
    const float* cw2   = (const float*)d_in[3];
    const float* cb2   = (const float*)d_in[4];
    const float* pw    = (const float*)d_in[5];
    const float* pb    = (const float*)d_in[6];
    const float* W_rec = (const float*)d_in[7];
    const float* W_in  = (const float*)d_in[8];
    const float* bias  = (const float*)d_in[9];
    const float* tau_b = (const float*)d_in[10];
    const float* tmw   = (const float*)d_in[11];
    const float* tmb   = (const float*)d_in[12];
    const float* ow    = (const float*)d_in[13];
    const float* ob    = (const float*)d_in[14];
    float* out = (float*)d_out;

    char* ws = (char*)d_ws;
    float*     alphas  = (float*)ws;                   // 192 f
    float*     h_carry = (float*)(ws + 1024);          // [3][64][256] f
    float*     bf      = (float*)(ws + 197632);        // 256 f
    float*     Wf      = (float*)(ws + 198656);        // 256*128 f
    _Float16*  wpk     = (_Float16*)(ws + 329728);     // [5][65536] f16
    float*     buf     = (float*)(ws + 1048576);       // [64][2048][256] f32 = 134.2MB

    prep_kernel<<<64, 1024, 0, stream>>>(x, cw1, cb1, cw2, cb2, tau_b, tmw, tmb, alphas, h_carry);
    wf_kernel<<<256, 128, 0, stream>>>(W_in, pw, pb, bias, Wf, bf);

    wpack_kernel<<<128, 64, 0, stream>>>(W_rec,          wpk);
    wpack_kernel<<<128, 64, 0, stream>>>(W_rec + 65536,  wpk + 65536);
    wpack_kernel<<<128, 64, 0, stream>>>(W_rec + 131072, wpk + 2 * 65536);
    wpack_kernel<<<128, 64, 0, stream>>>(W_in + 65536,   wpk + 3 * 65536);
    wpack_kernel<<<128, 64, 0, stream>>>(W_in + 131072,  wpk + 4 * 65536);

    // speculative chunked pipeline: gemm0 + 3 fused scans, spacing 1, CCH+3 stages
    for (int s = 0; s < CCH + 3; ++s)
        stage_kernel<<<256, 256, 0, stream>>>(s, buf, x, wpk, Wf, bf, bias, alphas, h_carry);

    outproj_kernel<<<64, 256, 0, stream>>>(h_carry + 2 * 16384, ow, ob, out);
}

// Round 23
// 1747.560 us; speedup vs baseline: 1.7807x; 1.2639x over previous
//
#include <hip/hip_runtime.h>
#include <hip/hip_bf16.h>
#include <math.h>
#include <type_traits>

#define HIDDEN 256
#define SEQ 2048
#define BATCH 64
#define INSZ 128
#define OUTSZ 64
#define DTC 0.05f
#define CCH 32           // pipeline chunks
#define CHS (SEQ / CCH)  // 64 steps per chunk
#define TBLK (CHS / 32)  // 2 gemm row-blocks per batch-chunk

typedef _Float16 f16x8 __attribute__((ext_vector_type(8)));
typedef float f32x4 __attribute__((ext_vector_type(4)));

// ---------------- K0: complexity net + alphas + zero h_carry slots ----------------
__global__ __launch_bounds__(1024) void prep_kernel(
    const float* __restrict__ x, const float* __restrict__ cw1, const float* __restrict__ cb1,
    const float* __restrict__ cw2, const float* __restrict__ cb2,
    const float* __restrict__ tau_b, const float* __restrict__ tmw, const float* __restrict__ tmb,
    float* __restrict__ alphas, float* __restrict__ h_carry)   // [3][64], [3][64][256]
{
    __shared__ float p_lds[8][128];
    __shared__ float xm[128];
    __shared__ float t1[64];
    int b = blockIdx.x;
    int tid = threadIdx.x;
    if (tid < 256) {
        h_carry[0 * 16384 + b * 256 + tid] = 0.f;
        h_carry[1 * 16384 + b * 256 + tid] = 0.f;
        h_carry[2 * 16384 + b * 256 + tid] = 0.f;
    }
    int c = tid & 127, sh = tid >> 7;
    const float* xb = x + (size_t)b * SEQ * INSZ;
    float s = 0.f;
    for (int t = sh * 256; t < (sh + 1) * 256; ++t) s += xb[(size_t)t * INSZ + c];
    p_lds[sh][c] = s;
    __syncthreads();
    if (tid < 128) {
        float m = 0.f;
        #pragma unroll
        for (int i = 0; i < 8; ++i) m += p_lds[i][tid];
        xm[tid] = m / (float)SEQ;
    }
    __syncthreads();
    if (tid < 64) {
        float acc = cb1[tid];
        for (int k = 0; k < 128; ++k) acc += xm[k] * cw1[tid * 128 + k];
        t1[tid] = fmaxf(acc, 0.f);
    }
    __syncthreads();
    if (tid == 0) {
        float acc = cb2[0];
        for (int k = 0; k < 64; ++k) acc += t1[k] * cw2[k];
        float comp = 1.f / (1.f + expf(-acc));
        for (int i = 0; i < 3; ++i) {
            float lg[4], mx = -1e30f;
            for (int j = 0; j < 4; ++j) { lg[j] = comp * tmw[i * 4 + j] + tmb[i * 4 + j]; mx = fmaxf(mx, lg[j]); }
            float den = 0.f;
            for (int j = 0; j < 4; ++j) { lg[j] = expf(lg[j] - mx); den += lg[j]; }
            float mt = 0.f;
            for (int j = 0; j < 4; ++j) mt += tau_b[i * 4 + j] * (lg[j] / den);
            alphas[i * 64 + b] = expf(-DTC / mt);
        }
    }
}

// ---------------- Wf = W_in0 @ pw  (256x128), bf = W_in0 @ pb + bias0 ----------------
__global__ __launch_bounds__(128) void wf_kernel(
    const float* __restrict__ W_in0, const float* __restrict__ pw,
    const float* __restrict__ pb, const float* __restrict__ bias0,
    float* __restrict__ Wf, float* __restrict__ bf)
{
    __shared__ float wrow[256];
    int j = blockIdx.x, k = threadIdx.x;
    for (int m = k; m < 256; m += 128) wrow[m] = W_in0[j * 256 + m];
    __syncthreads();
    float s = 0.f;
    for (int m = 0; m < 256; ++m) s = fmaf(wrow[m], pw[m * 128 + k], s);
    Wf[j * 128 + k] = s;
    if (k == 0) {
        float sb = bias0[j];
        for (int m = 0; m < 256; ++m) sb = fmaf(wrow[m], pb[m], sb);
        bf[j] = sb;
    }
}

__device__ __forceinline__ unsigned pkrtz(float a, float b) {
    return __builtin_bit_cast(unsigned, __builtin_amdgcn_cvt_pkrtz(a, b));
}

// ---------------- pack a 256x256 f32 matrix into per-lane f16 fragments ----------------
// P[(wave*4+mt)*8+kt][lane] (16B each): row = wave*64+mt*16+(lane&15), k = kt*32+(lane>>4)*8
__global__ __launch_bounds__(64) void wpack_kernel(
    const float* __restrict__ W, _Float16* __restrict__ P)
{
    int blk = blockIdx.x;            // (wave*4+mt)*8+kt, 128 blocks
    int wave = blk >> 5, mt = (blk >> 3) & 3, kt = blk & 7;
    int lane = threadIdx.x;
    int row = wave * 64 + mt * 16 + (lane & 15);
    int kcol = kt * 32 + (lane >> 4) * 8;
    const float4* s = (const float4*)(W + (size_t)row * 256 + kcol);
    float4 a = s[0], b = s[1];
    uint4 u = { pkrtz(a.x, a.y), pkrtz(a.z, a.w), pkrtz(b.x, b.y), pkrtz(b.z, b.w) };
    *(uint4*)((char*)P + (size_t)blk * 1024 + lane * 16) = u;
}

__device__ __forceinline__ float fast_tanh(float x) {
    float ex = __expf(2.f * x);
    float r = __builtin_amdgcn_rcpf(ex + 1.f);
    return 1.f - 2.f * r;
}

// LDS-only barrier: waits ds ops but leaves global loads/stores in flight.
__device__ __forceinline__ void barrier_lds_only() {
    asm volatile("s_waitcnt lgkmcnt(0)\n\ts_barrier" ::: "memory");
}

// ---------------- MFMA GEMM for ext0 (full seq; r17-verified) ----------------
__global__ __launch_bounds__(256, 2) void gemm0_kernel(
    const float* __restrict__ Asrc,  // x: f32 [M][128]
    const float* __restrict__ W,     // Wf [256][128] f32
    const float* __restrict__ bias,  // bf [256]
    float* __restrict__ C)           // buf [M][256] f32
{
    constexpr int KD = 128, KT = 4, ROWB = 256;
    __shared__ alignas(16) char alds[32 * ROWB];
    const int tid = threadIdx.x;
    const int wave = tid >> 6, lane = tid & 63;
    const int bl = lane & 15, q = lane >> 4;
    const int m0 = blockIdx.x * 32;

    f16x8 bfrag[4][KT];
    float bv[4];
    #pragma unroll
    for (int nt = 0; nt < 4; ++nt) {
        int n = wave * 64 + nt * 16 + bl;
        const float* wr = W + (size_t)n * KD;
        #pragma unroll
        for (int kt = 0; kt < KT; ++kt) {
            const float4* wp = (const float4*)(wr + kt * 32 + q * 8);
            float4 u0 = wp[0], u1 = wp[1];
            uint4 u = { pkrtz(u0.x, u0.y), pkrtz(u0.z, u0.w),
                        pkrtz(u1.x, u1.y), pkrtz(u1.z, u1.w) };
            bfrag[nt][kt] = __builtin_bit_cast(f16x8, u);
        }
        bv[nt] = bias[n];
    }
    #pragma unroll
    for (int it = 0; it < 2; ++it) {
        int idx = tid + it * 256;
        int row = idx >> 4, chunk = idx & 15;
        const float4* sp = (const float4*)(Asrc + (size_t)(m0 + row) * KD + chunk * 8);
        float4 f0 = sp[0], f1 = sp[1];
        uint4 u = { pkrtz(f0.x, f0.y), pkrtz(f0.z, f0.w),
                    pkrtz(f1.x, f1.y), pkrtz(f1.z, f1.w) };
        *(uint4*)(alds + row * ROWB + ((chunk * 16) ^ ((row & 7) << 4))) = u;
    }
    __syncthreads();

    f32x4 acc[2][4];
    #pragma unroll
    for (int mt = 0; mt < 2; ++mt)
        #pragma unroll
        for (int nt = 0; nt < 4; ++nt) acc[mt][nt] = (f32x4){0.f, 0.f, 0.f, 0.f};
    #pragma unroll
    for (int kt = 0; kt < KT; ++kt) {
        int inner = kt * 64 + q * 16;
        f16x8 a0 = __builtin_bit_cast(f16x8,
            *(const uint4*)(alds + (0 * 16 + bl) * ROWB + (inner ^ ((bl & 7) << 4))));
        f16x8 a1 = __builtin_bit_cast(f16x8,
            *(const uint4*)(alds + (1 * 16 + bl) * ROWB + (inner ^ ((bl & 7) << 4))));
        #pragma unroll
        for (int nt = 0; nt < 4; ++nt) {
            acc[0][nt] = __builtin_amdgcn_mfma_f32_16x16x32_f16(a0, bfrag[nt][kt], acc[0][nt], 0, 0, 0);
            acc[1][nt] = __builtin_amdgcn_mfma_f32_16x16x32_f16(a1, bfrag[nt][kt], acc[1][nt], 0, 0, 0);
        }
    }
    #pragma unroll
    for (int mt = 0; mt < 2; ++mt)
        #pragma unroll
        for (int nt = 0; nt < 4; ++nt) {
            int col = wave * 64 + nt * 16 + bl;
            #pragma unroll
            for (int r = 0; r < 4; ++r)
                C[(size_t)(m0 + mt * 16 + q * 4 + r) * 256 + col] = acc[mt][nt][r] + bv[nt];
        }
}

// ---------------- scan chunk: r19 body + split accumulation chains (2 x 4-deep) ----------------
__device__ __forceinline__ void scan_chunk(
    char* smem, float* buf, const _Float16* __restrict__ Wp,
    const float* __restrict__ alphas, float* __restrict__ h_carry,
    int b, int c, int write_all)
{
    _Float16 (*hlds)[256] = (_Float16 (*)[256])smem;   // [2][256]
    const int tid = threadIdx.x;
    const int wave = tid >> 6, lane = tid & 63;
    const int bl = lane & 15, q = lane >> 4;
    const int mt_own = bl >> 2, r_own = bl & 3;
    const int m = wave * 64 + mt_own * 16 + q * 4 + r_own;

    f16x8 afrag[4][8];
    #pragma unroll
    for (int mt = 0; mt < 4; ++mt)
        #pragma unroll
        for (int kt = 0; kt < 8; ++kt)
            afrag[mt][kt] = __builtin_bit_cast(f16x8,
                *(const uint4*)((const char*)Wp + (size_t)(((wave * 4 + mt) * 8 + kt) * 64 + lane) * 16));

    const float alpha = alphas[b], onema = 1.f - alpha;
    float* bb = buf + (size_t)b * SEQ * HIDDEN;
    const int t0 = c * CHS, tend = t0 + CHS;

    float h_reg = h_carry[b * 256 + m];    // true carry, or speculative 0 at chunk 0
    hlds[0][m] = (_Float16)h_reg;
    float e_cur = bb[(size_t)t0 * HIDDEN + m];
    float e_n1  = bb[(size_t)(t0 + 1) * HIDDEN + m];
    __syncthreads();

    auto step = [&](auto CB, int t) {
        constexpr int CUR = decltype(CB)::value;
        const char* rb = (const char*)&hlds[CUR][0];
        uint4 bq0 = *(const uint4*)(rb + q * 16);
        uint4 bq1 = *(const uint4*)(rb + 64 + q * 16);
        uint4 bq2 = *(const uint4*)(rb + 128 + q * 16);
        uint4 bq3 = *(const uint4*)(rb + 192 + q * 16);
        uint4 bq4 = *(const uint4*)(rb + 256 + q * 16);
        uint4 bq5 = *(const uint4*)(rb + 320 + q * 16);
        uint4 bq6 = *(const uint4*)(rb + 384 + q * 16);
        uint4 bq7 = *(const uint4*)(rb + 448 + q * 16);
        float e_n2 = 0.f;
        if (t + 2 < tend) e_n2 = bb[(size_t)(t + 2) * HIDDEN + m];

        // two independent 4-deep MFMA chains per m-tile: halves dependent-chain latency
        f32x4 ya0 = {0.f,0.f,0.f,0.f}, ya1 = {0.f,0.f,0.f,0.f};
        f32x4 ya2 = {0.f,0.f,0.f,0.f}, ya3 = {0.f,0.f,0.f,0.f};
        f32x4 yb0 = {0.f,0.f,0.f,0.f}, yb1 = {0.f,0.f,0.f,0.f};
        f32x4 yb2 = {0.f,0.f,0.f,0.f}, yb3 = {0.f,0.f,0.f,0.f};
        #define MSTEPA(BQ, KT) { f16x8 bf_ = __builtin_bit_cast(f16x8, BQ);                  \
            ya0 = __builtin_amdgcn_mfma_f32_16x16x32_f16(afrag[0][KT], bf_, ya0, 0, 0, 0);   \
            ya1 = __builtin_amdgcn_mfma_f32_16x16x32_f16(afrag[1][KT], bf_, ya1, 0, 0, 0);   \
            ya2 = __builtin_amdgcn_mfma_f32_16x16x32_f16(afrag[2][KT], bf_, ya2, 0, 0, 0);   \
            ya3 = __builtin_amdgcn_mfma_f32_16x16x32_f16(afrag[3][KT], bf_, ya3, 0, 0, 0); }
        #define MSTEPB(BQ, KT) { f16x8 bf_ = __builtin_bit_cast(f16x8, BQ);                  \
            yb0 = __builtin_amdgcn_mfma_f32_16x16x32_f16(afrag[0][KT], bf_, yb0, 0, 0, 0);   \
            yb1 = __builtin_amdgcn_mfma_f32_16x16x32_f16(afrag[1][KT], bf_, yb1, 0, 0, 0);   \
            yb2 = __builtin_amdgcn_mfma_f32_16x16x32_f16(afrag[2][KT], bf_, yb2, 0, 0, 0);   \
            yb3 = __builtin_amdgcn_mfma_f32_16x16x32_f16(afrag[3][KT], bf_, yb3, 0, 0, 0); }
        MSTEPA(bq0, 0) MSTEPB(bq4, 4) MSTEPA(bq1, 1) MSTEPB(bq5, 5)
        MSTEPA(bq2, 2) MSTEPB(bq6, 6) MSTEPA(bq3, 3) MSTEPB(bq7, 7)
        #undef MSTEPA
        #undef MSTEPB

        f32x4 am = (mt_own == 0) ? ya0 : (mt_own == 1) ? ya1 : (mt_own == 2) ? ya2 : ya3;
        f32x4 bm = (mt_own == 0) ? yb0 : (mt_own == 1) ? yb1 : (mt_own == 2) ? yb2 : yb3;
        float sa = (r_own == 0) ? am[0] : (r_own == 1) ? am[1] : (r_own == 2) ? am[2] : am[3];
        float sb = (r_own == 0) ? bm[0] : (r_own == 1) ? bm[1] : (r_own == 2) ? bm[2] : bm[3];

        float act = fast_tanh(sa + sb + e_cur);
        h_reg = alpha * h_reg + onema * act;
        hlds[CUR ^ 1][m] = (_Float16)h_reg;
        if (write_all)
            *((_Float16*)(bb + (size_t)t * HIDDEN) + m) = (_Float16)h_reg;
        barrier_lds_only();
        e_cur = e_n1;
        e_n1 = e_n2;
    };

    for (int t = t0; t < tend; t += 2) {
        step(std::integral_constant<int, 0>{}, t);
        step(std::integral_constant<int, 1>{}, t + 1);
    }
    h_carry[b * 256 + m] = h_reg;
}

// ---------------- ext GEMM: one block = 2 batches x TBLK tiles, weights loaded once (r19) ----------------
__device__ __forceinline__ void gemm_chunk4(
    char* smem, float* buf, const _Float16* __restrict__ Wp,
    const float* __restrict__ bias, int gl, int c)
{
    constexpr int KT = 8, ROWB = 512;
    char* alds = smem;   // 32 rows * 512B = 16 KB
    const int tid = threadIdx.x;
    const int wave = tid >> 6, lane = tid & 63;
    const int bl = lane & 15, q = lane >> 4;

    f16x8 bfrag[4][KT];
    float bv[4];
    #pragma unroll
    for (int nt = 0; nt < 4; ++nt) {
        #pragma unroll
        for (int kt = 0; kt < KT; ++kt)
            bfrag[nt][kt] = __builtin_bit_cast(f16x8,
                *(const uint4*)((const char*)Wp + (size_t)(((wave * 4 + nt) * 8 + kt) * 64 + lane) * 16));
        bv[nt] = bias[wave * 64 + nt * 16 + bl];
    }

    for (int u = 0; u < 2 * TBLK; ++u) {
        int b = 2 * gl + (u >> 1);
        int half = u & 1;
        size_t m0 = (size_t)b * SEQ + (size_t)c * CHS + (size_t)half * 32;

        __syncthreads();
        #pragma unroll
        for (int it = 0; it < 4; ++it) {
            int idx = tid + it * 256;
            int row = idx >> 5, chunk = idx & 31;
            uint4 uu = *(const uint4*)((const char*)buf + (m0 + row) * 1024 + chunk * 16);
            *(uint4*)(alds + row * ROWB + ((chunk * 16) ^ ((row & 7) << 4))) = uu;
        }
        __syncthreads();

        f32x4 acc[2][4];
        #pragma unroll
        for (int mt = 0; mt < 2; ++mt)
            #pragma unroll
            for (int nt = 0; nt < 4; ++nt) acc[mt][nt] = (f32x4){0.f, 0.f, 0.f, 0.f};
        #pragma unroll
        for (int kt = 0; kt < KT; ++kt) {
            int inner = kt * 64 + q * 16;
            f16x8 a0 = __builtin_bit_cast(f16x8,
                *(const uint4*)(alds + (0 * 16 + bl) * ROWB + (inner ^ ((bl & 7) << 4))));
            f16x8 a1 = __builtin_bit_cast(f16x8,
                *(const uint4*)(alds + (1 * 16 + bl) * ROWB + (inner ^ ((bl & 7) << 4))));
            #pragma unroll
            for (int nt = 0; nt < 4; ++nt) {
                acc[0][nt] = __builtin_amdgcn_mfma_f32_16x16x32_f16(a0, bfrag[nt][kt], acc[0][nt], 0, 0, 0);
                acc[1][nt] = __builtin_amdgcn_mfma_f32_16x16x32_f16(a1, bfrag[nt][kt], acc[1][nt], 0, 0, 0);
            }
        }
        #pragma unroll
        for (int mt = 0; mt < 2; ++mt)
            #pragma unroll
            for (int nt = 0; nt < 4; ++nt) {
                int col = wave * 64 + nt * 16 + bl;
                #pragma unroll
                for (int r = 0; r < 4; ++r)
                    buf[(m0 + mt * 16 + q * 4 + r) * 256 + col] = acc[mt][nt][r] + bv[nt];
            }
    }
}

// ---------------- stage megakernel (r19 structure, 256 blocks) ----------------
__global__ __launch_bounds__(256, 1) void stage_kernel(
    int stage, float* buf,
    const _Float16* __restrict__ wpk,   // [5][65536] packed: Wrec0,Wrec1,Wrec2,Win1,Win2
    const float* __restrict__ bias,  const float* __restrict__ alphas,
    float* __restrict__ h_carry)
{
    __shared__ alignas(16) char smem[16384];
    int blk = blockIdx.x;
    if (blk < 192) {
        int layer = blk >> 6;
        int c = stage - 2 * layer;
        if (c < 0 || c >= CCH) return;
        scan_chunk(smem, buf, wpk + (size_t)layer * 65536, alphas + layer * 64,
                   h_carry + (size_t)layer * 16384, blk & 63, c, layer < 2);
    } else {
        int g = blk - 192;
        int which = g >> 5;            // 0: ext1 gemm, 1: ext2 gemm
        int gl = g & 31;               // batch pair index
        int c = stage - 1 - 2 * which;
        if (c < 0 || c >= CCH) return;
        gemm_chunk4(smem, buf, wpk + (size_t)(3 + which) * 65536, bias + (which + 1) * 256, gl, c);
    }
}

// ---------------- final projection from h_carry[2] ----------------
__global__ __launch_bounds__(256) void outproj_kernel(
    const float* __restrict__ h_carry, const float* __restrict__ ow, const float* __restrict__ ob,
    float* __restrict__ out)
{
    __shared__ float h_l[256];
    __shared__ float p_lds[4][64];
    int b = blockIdx.x;
    int tid = threadIdx.x;
    h_l[tid] = h_carry[b * 256 + tid];
    __syncthreads();
    int o = tid & 63, qq = tid >> 6;
    float s = 0.f;
    const float4* wp = (const float4*)(ow + o * 256 + qq * 64);
    const float4* hp = (const float4*)(h_l + qq * 64);
    #pragma unroll
    for (int m = 0; m < 16; ++m) {
        float4 wv = wp[m]; float4 hv = hp[m];
        s = fmaf(wv.x, hv.x, s); s = fmaf(wv.y, hv.y, s);
        s = fmaf(wv.z, hv.z, s); s = fmaf(wv.w, hv.w, s);
    }
    p_lds[qq][o] = s;
    __syncthreads();
    if (tid < 64)
        out[b * 64 + tid] = p_lds[0][tid] + p_lds[1][tid] + p_lds[2][tid] + p_lds[3][tid] + ob[tid];
}

extern "C" void kernel_launch(void* const* d_in, const int* in_sizes, int n_in,
                              void* d_out, int out_size, void* d_ws, size_t ws_size,
                              hipStream_t stream)
{
    const float* x     = (const float*)d_in[0];
    const float* cw1   = (const float*)d_in[1];
    const float* cb1   = (const float*)d_in[2];
    const float* cw2   = (const float*)d_in[3];
    const float* cb2   = (const float*)d_in[4];
    const float* pw    = (const float*)d_in[5];
    const float* pb    = (const float*)d_in[6];
    const float* W_rec = (const float*)d_in[7];
    const float* W_in  = (const float*)d_in[8];
    const float* bias  = (const float*)d_in[9];
    const float* tau_b = (const float*)d_in[10];
    const float* tmw   = (const float*)d_in[11];
    const float* tmb   = (const float*)d_in[12];
    const float* ow    = (const float*)d_in[13];
    const float* ob    = (const float*)d_in[14];
    float* out = (float*)d_out;

    char* ws = (char*)d_ws;
    float*     alphas  = (float*)ws;                   // 192 f
    float*     h_carry = (float*)(ws + 1024);          // [3][64][256] f
    float*     bf      = (float*)(ws + 197632);        // 256 f
    float*     Wf      = (float*)(ws + 198656);        // 256*128 f
    _Float16*  wpk     = (_Float16*)(ws + 329728);     // [5][65536] f16
    float*     buf     = (float*)(ws + 1048576);       // [64][2048][256] f32 = 134.2MB

    const int MROWS = BATCH * SEQ;      // 131072
    const int NGBLK = 256;

    prep_kernel<<<64, 1024, 0, stream>>>(x, cw1, cb1, cw2, cb2, tau_b, tmw, tmb, alphas, h_carry);
    wf_kernel<<<256, 128, 0, stream>>>(W_in, pw, pb, bias, Wf, bf);

    wpack_kernel<<<128, 64, 0, stream>>>(W_rec,          wpk);
    wpack_kernel<<<128, 64, 0, stream>>>(W_rec + 65536,  wpk + 65536);
    wpack_kernel<<<128, 64, 0, stream>>>(W_rec + 131072, wpk + 2 * 65536);
    wpack_kernel<<<128, 64, 0, stream>>>(W_in + 65536,   wpk + 3 * 65536);
    wpack_kernel<<<128, 64, 0, stream>>>(W_in + 131072,  wpk + 4 * 65536);

    // ext0 = x @ Wf.T + bf (input projection + W_in0 fused), full sequence
    gemm0_kernel<<<MROWS / 32, 256, 0, stream>>>(x, Wf, bf, buf);

    // speculative chunked pipeline: 3 scans + 2 ext-gemms overlapped across launches
    for (int s = 0; s < CCH + 4; ++s)
        stage_kernel<<<NGBLK, 256, 0, stream>>>(s, buf, wpk, bias, alphas, h_carry);

    outproj_kernel<<<64, 256, 0, stream>>>(h_carry + 2 * 16384, ow, ob, out);
}

// Round 24
// 1448.820 us; speedup vs baseline: 2.1478x; 1.2062x over previous
//
#include <hip/hip_runtime.h>
#include <hip/hip_bf16.h>
#include <math.h>
#include <type_traits>

#define HIDDEN 256
#define SEQ 2048
#define BATCH 64
#define INSZ 128
#define OUTSZ 64
#define DTC 0.05f
#define CCH 32           // pipeline chunks
#define CHS (SEQ / CCH)  // 64 steps per chunk
#define TBLK (CHS / 32)  // 2 gemm row-blocks per batch-chunk

typedef _Float16 f16x8 __attribute__((ext_vector_type(8)));
typedef float f32x4 __attribute__((ext_vector_type(4)));

// ---------------- K0: complexity net + alphas + zero h_carry slots ----------------
__global__ __launch_bounds__(1024) void prep_kernel(
    const float* __restrict__ x, const float* __restrict__ cw1, const float* __restrict__ cb1,
    const float* __restrict__ cw2, const float* __restrict__ cb2,
    const float* __restrict__ tau_b, const float* __restrict__ tmw, const float* __restrict__ tmb,
    float* __restrict__ alphas, float* __restrict__ h_carry)   // [3][64], [3][64][256]
{
    __shared__ float p_lds[8][128];
    __shared__ float xm[128];
    __shared__ float t1[64];
    int b = blockIdx.x;
    int tid = threadIdx.x;
    if (tid < 256) {
        h_carry[0 * 16384 + b * 256 + tid] = 0.f;
        h_carry[1 * 16384 + b * 256 + tid] = 0.f;
        h_carry[2 * 16384 + b * 256 + tid] = 0.f;
    }
    int c = tid & 127, sh = tid >> 7;
    const float* xb = x + (size_t)b * SEQ * INSZ;
    float s = 0.f;
    for (int t = sh * 256; t < (sh + 1) * 256; ++t) s += xb[(size_t)t * INSZ + c];
    p_lds[sh][c] = s;
    __syncthreads();
    if (tid < 128) {
        float m = 0.f;
        #pragma unroll
        for (int i = 0; i < 8; ++i) m += p_lds[i][tid];
        xm[tid] = m / (float)SEQ;
    }
    __syncthreads();
    if (tid < 64) {
        float acc = cb1[tid];
        for (int k = 0; k < 128; ++k) acc += xm[k] * cw1[tid * 128 + k];
        t1[tid] = fmaxf(acc, 0.f);
    }
    __syncthreads();
    if (tid == 0) {
        float acc = cb2[0];
        for (int k = 0; k < 64; ++k) acc += t1[k] * cw2[k];
        float comp = 1.f / (1.f + expf(-acc));
        for (int i = 0; i < 3; ++i) {
            float lg[4], mx = -1e30f;
            for (int j = 0; j < 4; ++j) { lg[j] = comp * tmw[i * 4 + j] + tmb[i * 4 + j]; mx = fmaxf(mx, lg[j]); }
            float den = 0.f;
            for (int j = 0; j < 4; ++j) { lg[j] = expf(lg[j] - mx); den += lg[j]; }
            float mt = 0.f;
            for (int j = 0; j < 4; ++j) mt += tau_b[i * 4 + j] * (lg[j] / den);
            alphas[i * 64 + b] = expf(-DTC / mt);
        }
    }
}

// ---------------- Wf = W_in0 @ pw  (256x128), bf = W_in0 @ pb + bias0 ----------------
__global__ __launch_bounds__(128) void wf_kernel(
    const float* __restrict__ W_in0, const float* __restrict__ pw,
    const float* __restrict__ pb, const float* __restrict__ bias0,
    float* __restrict__ Wf, float* __restrict__ bf)
{
    __shared__ float wrow[256];
    int j = blockIdx.x, k = threadIdx.x;
    for (int m = k; m < 256; m += 128) wrow[m] = W_in0[j * 256 + m];
    __syncthreads();
    float s = 0.f;
    for (int m = 0; m < 256; ++m) s = fmaf(wrow[m], pw[m * 128 + k], s);
    Wf[j * 128 + k] = s;
    if (k == 0) {
        float sb = bias0[j];
        for (int m = 0; m < 256; ++m) sb = fmaf(wrow[m], pb[m], sb);
        bf[j] = sb;
    }
}

__device__ __forceinline__ unsigned pkrtz(float a, float b) {
    return __builtin_bit_cast(unsigned, __builtin_amdgcn_cvt_pkrtz(a, b));
}

// ---------------- pack a 256x256 f32 matrix into per-lane f16 fragments ----------------
__global__ __launch_bounds__(64) void wpack_kernel(
    const float* __restrict__ W, _Float16* __restrict__ P)
{
    int blk = blockIdx.x;            // (wave*4+mt)*8+kt, 128 blocks
    int wave = blk >> 5, mt = (blk >> 3) & 3, kt = blk & 7;
    int lane = threadIdx.x;
    int row = wave * 64 + mt * 16 + (lane & 15);
    int kcol = kt * 32 + (lane >> 4) * 8;
    const float4* s = (const float4*)(W + (size_t)row * 256 + kcol);
    float4 a = s[0], b = s[1];
    uint4 u = { pkrtz(a.x, a.y), pkrtz(a.z, a.w), pkrtz(b.x, b.y), pkrtz(b.z, b.w) };
    *(uint4*)((char*)P + (size_t)blk * 1024 + lane * 16) = u;
}

__device__ __forceinline__ float fast_tanh(float x) {
    float ex = __expf(2.f * x);
    float r = __builtin_amdgcn_rcpf(ex + 1.f);
    return 1.f - 2.f * r;
}

// LDS-only barrier: waits ds ops but leaves global loads/stores in flight.
__device__ __forceinline__ void barrier_lds_only() {
    asm volatile("s_waitcnt lgkmcnt(0)\n\ts_barrier" ::: "memory");
}

// ---------------- scan chunk (r19 body, single 8-deep chain; afrag from packed f16) ----------------
__device__ __forceinline__ void scan_chunk(
    char* smem, float* buf, const _Float16* __restrict__ Wp,
    const float* __restrict__ alphas, float* __restrict__ h_carry,
    int b, int c, int write_all)
{
    _Float16 (*hlds)[256] = (_Float16 (*)[256])smem;   // [2][256]
    const int tid = threadIdx.x;
    const int wave = tid >> 6, lane = tid & 63;
    const int bl = lane & 15, q = lane >> 4;
    const int mt_own = bl >> 2, r_own = bl & 3;
    const int m = wave * 64 + mt_own * 16 + q * 4 + r_own;

    f16x8 afrag[4][8];
    #pragma unroll
    for (int mt = 0; mt < 4; ++mt)
        #pragma unroll
        for (int kt = 0; kt < 8; ++kt)
            afrag[mt][kt] = __builtin_bit_cast(f16x8,
                *(const uint4*)((const char*)Wp + (size_t)(((wave * 4 + mt) * 8 + kt) * 64 + lane) * 16));

    const float alpha = alphas[b], onema = 1.f - alpha;
    float* bb = buf + (size_t)b * SEQ * HIDDEN;
    const int t0 = c * CHS, tend = t0 + CHS;

    float h_reg = h_carry[b * 256 + m];    // true carry, or speculative 0 at chunk 0
    hlds[0][m] = (_Float16)h_reg;
    float e_cur = bb[(size_t)t0 * HIDDEN + m];
    float e_n1  = bb[(size_t)(t0 + 1) * HIDDEN + m];
    __syncthreads();

    auto step = [&](auto CB, int t) {
        constexpr int CUR = decltype(CB)::value;
        const char* rb = (const char*)&hlds[CUR][0];
        uint4 bq0 = *(const uint4*)(rb + q * 16);
        uint4 bq1 = *(const uint4*)(rb + 64 + q * 16);
        uint4 bq2 = *(const uint4*)(rb + 128 + q * 16);
        uint4 bq3 = *(const uint4*)(rb + 192 + q * 16);
        uint4 bq4 = *(const uint4*)(rb + 256 + q * 16);
        uint4 bq5 = *(const uint4*)(rb + 320 + q * 16);
        uint4 bq6 = *(const uint4*)(rb + 384 + q * 16);
        uint4 bq7 = *(const uint4*)(rb + 448 + q * 16);
        float e_n2 = 0.f;
        if (t + 2 < tend) e_n2 = bb[(size_t)(t + 2) * HIDDEN + m];

        f32x4 a0 = {0.f,0.f,0.f,0.f}, a1 = {0.f,0.f,0.f,0.f};
        f32x4 a2 = {0.f,0.f,0.f,0.f}, a3 = {0.f,0.f,0.f,0.f};
        #define MSTEP(BQ, KT) { f16x8 bf_ = __builtin_bit_cast(f16x8, BQ);                 \
            a0 = __builtin_amdgcn_mfma_f32_16x16x32_f16(afrag[0][KT], bf_, a0, 0, 0, 0);   \
            a1 = __builtin_amdgcn_mfma_f32_16x16x32_f16(afrag[1][KT], bf_, a1, 0, 0, 0);   \
            a2 = __builtin_amdgcn_mfma_f32_16x16x32_f16(afrag[2][KT], bf_, a2, 0, 0, 0);   \
            a3 = __builtin_amdgcn_mfma_f32_16x16x32_f16(afrag[3][KT], bf_, a3, 0, 0, 0); }
        MSTEP(bq0, 0) MSTEP(bq1, 1) MSTEP(bq2, 2) MSTEP(bq3, 3)
        MSTEP(bq4, 4) MSTEP(bq5, 5) MSTEP(bq6, 6) MSTEP(bq7, 7)
        #undef MSTEP

        f32x4 am = (mt_own == 0) ? a0 : (mt_own == 1) ? a1 : (mt_own == 2) ? a2 : a3;
        float sv = (r_own == 0) ? am[0] : (r_own == 1) ? am[1] : (r_own == 2) ? am[2] : am[3];

        float act = fast_tanh(sv + e_cur);
        h_reg = alpha * h_reg + onema * act;
        hlds[CUR ^ 1][m] = (_Float16)h_reg;
        if (write_all)
            *((_Float16*)(bb + (size_t)t * HIDDEN) + m) = (_Float16)h_reg;
        barrier_lds_only();
        e_cur = e_n1;
        e_n1 = e_n2;
    };

    for (int t = t0; t < tend; t += 2) {
        step(std::integral_constant<int, 0>{}, t);
        step(std::integral_constant<int, 1>{}, t + 1);
    }
    h_carry[b * 256 + m] = h_reg;
}

// ---------------- ext GEMM: one block = 2 batches x TBLK tiles, weights loaded once (r19) ----------------
__device__ __forceinline__ void gemm_chunk4(
    char* smem, float* buf, const _Float16* __restrict__ Wp,
    const float* __restrict__ bias, int gl, int c)
{
    constexpr int KT = 8, ROWB = 512;
    char* alds = smem;   // 32 rows * 512B = 16 KB
    const int tid = threadIdx.x;
    const int wave = tid >> 6, lane = tid & 63;
    const int bl = lane & 15, q = lane >> 4;

    f16x8 bfrag[4][KT];
    float bv[4];
    #pragma unroll
    for (int nt = 0; nt < 4; ++nt) {
        #pragma unroll
        for (int kt = 0; kt < KT; ++kt)
            bfrag[nt][kt] = __builtin_bit_cast(f16x8,
                *(const uint4*)((const char*)Wp + (size_t)(((wave * 4 + nt) * 8 + kt) * 64 + lane) * 16));
        bv[nt] = bias[wave * 64 + nt * 16 + bl];
    }

    for (int u = 0; u < 2 * TBLK; ++u) {
        int b = 2 * gl + (u >> 1);
        int half = u & 1;
        size_t m0 = (size_t)b * SEQ + (size_t)c * CHS + (size_t)half * 32;

        __syncthreads();
        #pragma unroll
        for (int it = 0; it < 4; ++it) {
            int idx = tid + it * 256;
            int row = idx >> 5, chunk = idx & 31;
            uint4 uu = *(const uint4*)((const char*)buf + (m0 + row) * 1024 + chunk * 16);
            *(uint4*)(alds + row * ROWB + ((chunk * 16) ^ ((row & 7) << 4))) = uu;
        }
        __syncthreads();

        f32x4 acc[2][4];
        #pragma unroll
        for (int mt = 0; mt < 2; ++mt)
            #pragma unroll
            for (int nt = 0; nt < 4; ++nt) acc[mt][nt] = (f32x4){0.f, 0.f, 0.f, 0.f};
        #pragma unroll
        for (int kt = 0; kt < KT; ++kt) {
            int inner = kt * 64 + q * 16;
            f16x8 a0 = __builtin_bit_cast(f16x8,
                *(const uint4*)(alds + (0 * 16 + bl) * ROWB + (inner ^ ((bl & 7) << 4))));
            f16x8 a1 = __builtin_bit_cast(f16x8,
                *(const uint4*)(alds + (1 * 16 + bl) * ROWB + (inner ^ ((bl & 7) << 4))));
            #pragma unroll
            for (int nt = 0; nt < 4; ++nt) {
                acc[0][nt] = __builtin_amdgcn_mfma_f32_16x16x32_f16(a0, bfrag[nt][kt], acc[0][nt], 0, 0, 0);
                acc[1][nt] = __builtin_amdgcn_mfma_f32_16x16x32_f16(a1, bfrag[nt][kt], acc[1][nt], 0, 0, 0);
            }
        }
        #pragma unroll
        for (int mt = 0; mt < 2; ++mt)
            #pragma unroll
            for (int nt = 0; nt < 4; ++nt) {
                int col = wave * 64 + nt * 16 + bl;
                #pragma unroll
                for (int r = 0; r < 4; ++r)
                    buf[(m0 + mt * 16 + q * 4 + r) * 256 + col] = acc[mt][nt][r] + bv[nt];
            }
    }
}

// ---------------- gemm0 chunk: ext0 = x @ Wf.T + bf for one (batch, chunk) = 64 rows ----------------
__device__ __forceinline__ void gemm0_chunk(
    char* smem, const float* __restrict__ x, const float* __restrict__ Wf,
    const float* __restrict__ bf, float* __restrict__ buf, int gl, int c)
{
    constexpr int KD = 128, KT = 4, ROWB = 256;
    char* alds = smem;   // 32 rows * 256B = 8 KB
    const int tid = threadIdx.x;
    const int wave = tid >> 6, lane = tid & 63;
    const int bl = lane & 15, q = lane >> 4;

    f16x8 bfrag[4][KT];
    float bv[4];
    #pragma unroll
    for (int nt = 0; nt < 4; ++nt) {
        int n = wave * 64 + nt * 16 + bl;
        const float* wr = Wf + (size_t)n * KD;
        #pragma unroll
        for (int kt = 0; kt < KT; ++kt) {
            const float4* wp = (const float4*)(wr + kt * 32 + q * 8);
            float4 u0 = wp[0], u1 = wp[1];
            uint4 u = { pkrtz(u0.x, u0.y), pkrtz(u0.z, u0.w),
                        pkrtz(u1.x, u1.y), pkrtz(u1.z, u1.w) };
            bfrag[nt][kt] = __builtin_bit_cast(f16x8, u);
        }
        bv[nt] = bf[n];
    }

    for (int half = 0; half < 2; ++half) {
        size_t m0 = (size_t)gl * SEQ + (size_t)c * CHS + (size_t)half * 32;
        const float* Asrc = x + m0 * KD;

        __syncthreads();
        #pragma unroll
        for (int it = 0; it < 2; ++it) {
            int idx = tid + it * 256;
            int row = idx >> 4, chunk = idx & 15;
            const float4* sp = (const float4*)(Asrc + (size_t)row * KD + chunk * 8);
            float4 f0 = sp[0], f1 = sp[1];
            uint4 u = { pkrtz(f0.x, f0.y), pkrtz(f0.z, f0.w),
                        pkrtz(f1.x, f1.y), pkrtz(f1.z, f1.w) };
            *(uint4*)(alds + row * ROWB + ((chunk * 16) ^ ((row & 7) << 4))) = u;
        }
        __syncthreads();

        f32x4 acc[2][4];
        #pragma unroll
        for (int mt = 0; mt < 2; ++mt)
            #pragma unroll
            for (int nt = 0; nt < 4; ++nt) acc[mt][nt] = (f32x4){0.f, 0.f, 0.f, 0.f};
        #pragma unroll
        for (int kt = 0; kt < KT; ++kt) {
            int inner = kt * 64 + q * 16;
            f16x8 a0 = __builtin_bit_cast(f16x8,
                *(const uint4*)(alds + (0 * 16 + bl) * ROWB + (inner ^ ((bl & 7) << 4))));
            f16x8 a1 = __builtin_bit_cast(f16x8,
                *(const uint4*)(alds + (1 * 16 + bl) * ROWB + (inner ^ ((bl & 7) << 4))));
            #pragma unroll
            for (int nt = 0; nt < 4; ++nt) {
                acc[0][nt] = __builtin_amdgcn_mfma_f32_16x16x32_f16(a0, bfrag[nt][kt], acc[0][nt], 0, 0, 0);
                acc[1][nt] = __builtin_amdgcn_mfma_f32_16x16x32_f16(a1, bfrag[nt][kt], acc[1][nt], 0, 0, 0);
            }
        }
        #pragma unroll
        for (int mt = 0; mt < 2; ++mt)
            #pragma unroll
            for (int nt = 0; nt < 4; ++nt) {
                int col = wave * 64 + nt * 16 + bl;
                #pragma unroll
                for (int r = 0; r < 4; ++r)
                    buf[(m0 + mt * 16 + q * 4 + r) * 256 + col] = acc[mt][nt][r] + bv[nt];
            }
    }
}

// ---------------- stage megakernel: 320 blocks ----------------
// [0,64): scanL0(c=s-1); [64,128): scanL1(c=s-3); [128,192): scanL2(c=s-5);
// [192,224): gemm1(c=s-2); [224,256): gemm2(c=s-4); [256,320): gemm0(c=s).
__global__ __launch_bounds__(256, 1) void stage_kernel(
    int stage, float* buf, const float* __restrict__ x,
    const _Float16* __restrict__ wpk,   // [5][65536] packed: Wrec0,Wrec1,Wrec2,Win1,Win2
    const float* __restrict__ Wf, const float* __restrict__ bf,
    const float* __restrict__ bias,  const float* __restrict__ alphas,
    float* __restrict__ h_carry)
{
    __shared__ alignas(16) char smem[16384];
    int blk = blockIdx.x;
    if (blk < 192) {
        int layer = blk >> 6;
        int c = stage - 1 - 2 * layer;
        if (c < 0 || c >= CCH) return;
        scan_chunk(smem, buf, wpk + (size_t)layer * 65536, alphas + layer * 64,
                   h_carry + (size_t)layer * 16384, blk & 63, c, layer < 2);
    } else if (blk < 256) {
        int g = blk - 192;
        int which = g >> 5;            // 0: ext1 gemm, 1: ext2 gemm
        int gl = g & 31;               // batch pair index
        int c = stage - 2 - 2 * which;
        if (c < 0 || c >= CCH) return;
        gemm_chunk4(smem, buf, wpk + (size_t)(3 + which) * 65536, bias + (which + 1) * 256, gl, c);
    } else {
        int gl = blk - 256;            // one batch per block
        int c = stage;
        if (c >= CCH) return;
        gemm0_chunk(smem, x, Wf, bf, buf, gl, c);
    }
}

// ---------------- final projection from h_carry[2] ----------------
__global__ __launch_bounds__(256) void outproj_kernel(
    const float* __restrict__ h_carry, const float* __restrict__ ow, const float* __restrict__ ob,
    float* __restrict__ out)
{
    __shared__ float h_l[256];
    __shared__ float p_lds[4][64];
    int b = blockIdx.x;
    int tid = threadIdx.x;
    h_l[tid] = h_carry[b * 256 + tid];
    __syncthreads();
    int o = tid & 63, qq = tid >> 6;
    float s = 0.f;
    const float4* wp = (const float4*)(ow + o * 256 + qq * 64);
    const float4* hp = (const float4*)(h_l + qq * 64);
    #pragma unroll
    for (int m = 0; m < 16; ++m) {
        float4 wv = wp[m]; float4 hv = hp[m];
        s = fmaf(wv.x, hv.x, s); s = fmaf(wv.y, hv.y, s);
        s = fmaf(wv.z, hv.z, s); s = fmaf(wv.w, hv.w, s);
    }
    p_lds[qq][o] = s;
    __syncthreads();
    if (tid < 64)
        out[b * 64 + tid] = p_lds[0][tid] + p_lds[1][tid] + p_lds[2][tid] + p_lds[3][tid] + ob[tid];
}

extern "C" void kernel_launch(void* const* d_in, const int* in_sizes, int n_in,
                              void* d_out, int out_size, void* d_ws, size_t ws_size,
                              hipStream_t stream)
{
    const float* x     = (const float*)d_in[0];
    const float* cw1   = (const float*)d_in[1];
    const float* cb1   = (const float*)d_in[2];
    const float* cw2   = (const float*)d_in[3];
    const float* cb2   = (const float*)d_in[4];
    const float* pw    = (const float*)d_in[5];
    const float* pb    = (const float*)d_in[6];
    const float* W_rec = (const float*)d_in[7];
    const float* W_in  = (const float*)d_in[8];
    const float* bias  = (const float*)d_in[9];
    const float* tau_b = (const float*)d_in[10];
    const float* tmw   = (const float*)d_in[11];
    const float* tmb   = (const float*)d_in[12];
    const float* ow    = (const float*)d_in[13];
    const float* ob    = (const float*)d_in[14];
    float* out = (float*)d_out;

    char* ws = (char*)d_ws;
    float*     alphas  = (float*)ws;                   // 192 f
    float*     h_carry = (float*)(ws + 1024);          // [3][64][256] f
    float*     bf      = (float*)(ws + 197632);        // 256 f
    float*     Wf      = (float*)(ws + 198656);        // 256*128 f
    _Float16*  wpk     = (_Float16*)(ws + 329728);     // [5][65536] f16
    float*     buf     = (float*)(ws + 1048576);       // [64][2048][256] f32 = 134.2MB

    prep_kernel<<<64, 1024, 0, stream>>>(x, cw1, cb1, cw2, cb2, tau_b, tmw, tmb, alphas, h_carry);
    wf_kernel<<<256, 128, 0, stream>>>(W_in, pw, pb, bias, Wf, bf);

    wpack_kernel<<<128, 64, 0, stream>>>(W_rec,          wpk);
    wpack_kernel<<<128, 64, 0, stream>>>(W_rec + 65536,  wpk + 65536);
    wpack_kernel<<<128, 64, 0, stream>>>(W_rec + 131072, wpk + 2 * 65536);
    wpack_kernel<<<128, 64, 0, stream>>>(W_in + 65536,   wpk + 3 * 65536);
    wpack_kernel<<<128, 64, 0, stream>>>(W_in + 131072,  wpk + 4 * 65536);

    // fully-pipelined: gemm0 + 3 scans + 2 ext-gemms, deps ride launch order
    for (int s = 0; s < CCH + 6; ++s)
        stage_kernel<<<320, 256, 0, stream>>>(s, buf, x, wpk, Wf, bf, bias, alphas, h_carry);

    outproj_kernel<<<64, 256, 0, stream>>>(h_carry + 2 * 16384, ow, ob, out);
}

// Round 25
// 1392.787 us; speedup vs baseline: 2.2342x; 1.0402x over previous
//
#include <hip/hip_runtime.h>
#include <hip/hip_bf16.h>
#include <math.h>
#include <type_traits>

#define HIDDEN 256
#define SEQ 2048
#define BATCH 64
#define INSZ 128
#define OUTSZ 64
#define DTC 0.05f
#define CCH 32           // pipeline chunks
#define CHS (SEQ / CCH)  // 64 steps per chunk
#define TBLK (CHS / 32)  // 2 gemm row-blocks per batch-chunk

typedef _Float16 f16x8 __attribute__((ext_vector_type(8)));
typedef float f32x4 __attribute__((ext_vector_type(4)));

// ---------------- K0: complexity net + alphas + zero h_carry slots ----------------
__global__ __launch_bounds__(1024) void prep_kernel(
    const float* __restrict__ x, const float* __restrict__ cw1, const float* __restrict__ cb1,
    const float* __restrict__ cw2, const float* __restrict__ cb2,
    const float* __restrict__ tau_b, const float* __restrict__ tmw, const float* __restrict__ tmb,
    float* __restrict__ alphas, float* __restrict__ h_carry)   // [3][64], [3][64][256]
{
    __shared__ float p_lds[8][128];
    __shared__ float xm[128];
    __shared__ float t1[64];
    int b = blockIdx.x;
    int tid = threadIdx.x;
    if (tid < 256) {
        h_carry[0 * 16384 + b * 256 + tid] = 0.f;
        h_carry[1 * 16384 + b * 256 + tid] = 0.f;
        h_carry[2 * 16384 + b * 256 + tid] = 0.f;
    }
    int c = tid & 127, sh = tid >> 7;
    const float* xb = x + (size_t)b * SEQ * INSZ;
    float s = 0.f;
    for (int t = sh * 256; t < (sh + 1) * 256; ++t) s += xb[(size_t)t * INSZ + c];
    p_lds[sh][c] = s;
    __syncthreads();
    if (tid < 128) {
        float m = 0.f;
        #pragma unroll
        for (int i = 0; i < 8; ++i) m += p_lds[i][tid];
        xm[tid] = m / (float)SEQ;
    }
    __syncthreads();
    if (tid < 64) {
        float acc = cb1[tid];
        for (int k = 0; k < 128; ++k) acc += xm[k] * cw1[tid * 128 + k];
        t1[tid] = fmaxf(acc, 0.f);
    }
    __syncthreads();
    if (tid == 0) {
        float acc = cb2[0];
        for (int k = 0; k < 64; ++k) acc += t1[k] * cw2[k];
        float comp = 1.f / (1.f + expf(-acc));
        for (int i = 0; i < 3; ++i) {
            float lg[4], mx = -1e30f;
            for (int j = 0; j < 4; ++j) { lg[j] = comp * tmw[i * 4 + j] + tmb[i * 4 + j]; mx = fmaxf(mx, lg[j]); }
            float den = 0.f;
            for (int j = 0; j < 4; ++j) { lg[j] = expf(lg[j] - mx); den += lg[j]; }
            float mt = 0.f;
            for (int j = 0; j < 4; ++j) mt += tau_b[i * 4 + j] * (lg[j] / den);
            alphas[i * 64 + b] = expf(-DTC / mt);
        }
    }
}

// ---------------- Wf = W_in0 @ pw  (256x128), bf = W_in0 @ pb + bias0 ----------------
__global__ __launch_bounds__(128) void wf_kernel(
    const float* __restrict__ W_in0, const float* __restrict__ pw,
    const float* __restrict__ pb, const float* __restrict__ bias0,
    float* __restrict__ Wf, float* __restrict__ bf)
{
    __shared__ float wrow[256];
    int j = blockIdx.x, k = threadIdx.x;
    for (int m = k; m < 256; m += 128) wrow[m] = W_in0[j * 256 + m];
    __syncthreads();
    float s = 0.f;
    for (int m = 0; m < 256; ++m) s = fmaf(wrow[m], pw[m * 128 + k], s);
    Wf[j * 128 + k] = s;
    if (k == 0) {
        float sb = bias0[j];
        for (int m = 0; m < 256; ++m) sb = fmaf(wrow[m], pb[m], sb);
        bf[j] = sb;
    }
}

__device__ __forceinline__ unsigned pkrtz(float a, float b) {
    return __builtin_bit_cast(unsigned, __builtin_amdgcn_cvt_pkrtz(a, b));
}

// ---------------- pack a 256x256 f32 matrix into per-lane f16 fragments ----------------
__global__ __launch_bounds__(64) void wpack_kernel(
    const float* __restrict__ W, _Float16* __restrict__ P)
{
    int blk = blockIdx.x;            // (wave*4+mt)*8+kt, 128 blocks
    int wave = blk >> 5, mt = (blk >> 3) & 3, kt = blk & 7;
    int lane = threadIdx.x;
    int row = wave * 64 + mt * 16 + (lane & 15);
    int kcol = kt * 32 + (lane >> 4) * 8;
    const float4* s = (const float4*)(W + (size_t)row * 256 + kcol);
    float4 a = s[0], b = s[1];
    uint4 u = { pkrtz(a.x, a.y), pkrtz(a.z, a.w), pkrtz(b.x, b.y), pkrtz(b.z, b.w) };
    *(uint4*)((char*)P + (size_t)blk * 1024 + lane * 16) = u;
}

__device__ __forceinline__ float fast_tanh(float x) {
    float ex = __expf(2.f * x);
    float r = __builtin_amdgcn_rcpf(ex + 1.f);
    return 1.f - 2.f * r;
}

// LDS-only barrier: waits ds ops but leaves global loads/stores in flight.
__device__ __forceinline__ void barrier_lds_only() {
    asm volatile("s_waitcnt lgkmcnt(0)\n\ts_barrier" ::: "memory");
}

// ---------------- scan chunk (r19 body, single 8-deep chain; afrag from packed f16) ----------------
__device__ __forceinline__ void scan_chunk(
    char* smem, float* buf, const _Float16* __restrict__ Wp,
    const float* __restrict__ alphas, float* __restrict__ h_carry,
    int b, int c, int write_all)
{
    _Float16 (*hlds)[256] = (_Float16 (*)[256])smem;   // [2][256]
    const int tid = threadIdx.x;
    const int wave = tid >> 6, lane = tid & 63;
    const int bl = lane & 15, q = lane >> 4;
    const int mt_own = bl >> 2, r_own = bl & 3;
    const int m = wave * 64 + mt_own * 16 + q * 4 + r_own;

    f16x8 afrag[4][8];
    #pragma unroll
    for (int mt = 0; mt < 4; ++mt)
        #pragma unroll
        for (int kt = 0; kt < 8; ++kt)
            afrag[mt][kt] = __builtin_bit_cast(f16x8,
                *(const uint4*)((const char*)Wp + (size_t)(((wave * 4 + mt) * 8 + kt) * 64 + lane) * 16));

    const float alpha = alphas[b], onema = 1.f - alpha;
    float* bb = buf + (size_t)b * SEQ * HIDDEN;
    const int t0 = c * CHS, tend = t0 + CHS;

    float h_reg = h_carry[b * 256 + m];    // true carry, or speculative 0 at chunk 0
    hlds[0][m] = (_Float16)h_reg;
    float e_cur = bb[(size_t)t0 * HIDDEN + m];
    float e_n1  = bb[(size_t)(t0 + 1) * HIDDEN + m];
    __syncthreads();

    auto step = [&](auto CB, int t) {
        constexpr int CUR = decltype(CB)::value;
        const char* rb = (const char*)&hlds[CUR][0];
        uint4 bq0 = *(const uint4*)(rb + q * 16);
        uint4 bq1 = *(const uint4*)(rb + 64 + q * 16);
        uint4 bq2 = *(const uint4*)(rb + 128 + q * 16);
        uint4 bq3 = *(const uint4*)(rb + 192 + q * 16);
        uint4 bq4 = *(const uint4*)(rb + 256 + q * 16);
        uint4 bq5 = *(const uint4*)(rb + 320 + q * 16);
        uint4 bq6 = *(const uint4*)(rb + 384 + q * 16);
        uint4 bq7 = *(const uint4*)(rb + 448 + q * 16);
        float e_n2 = 0.f;
        if (t + 2 < tend) e_n2 = bb[(size_t)(t + 2) * HIDDEN + m];

        f32x4 a0 = {0.f,0.f,0.f,0.f}, a1 = {0.f,0.f,0.f,0.f};
        f32x4 a2 = {0.f,0.f,0.f,0.f}, a3 = {0.f,0.f,0.f,0.f};
        #define MSTEP(BQ, KT) { f16x8 bf_ = __builtin_bit_cast(f16x8, BQ);                 \
            a0 = __builtin_amdgcn_mfma_f32_16x16x32_f16(afrag[0][KT], bf_, a0, 0, 0, 0);   \
            a1 = __builtin_amdgcn_mfma_f32_16x16x32_f16(afrag[1][KT], bf_, a1, 0, 0, 0);   \
            a2 = __builtin_amdgcn_mfma_f32_16x16x32_f16(afrag[2][KT], bf_, a2, 0, 0, 0);   \
            a3 = __builtin_amdgcn_mfma_f32_16x16x32_f16(afrag[3][KT], bf_, a3, 0, 0, 0); }
        MSTEP(bq0, 0) MSTEP(bq1, 1) MSTEP(bq2, 2) MSTEP(bq3, 3)
        MSTEP(bq4, 4) MSTEP(bq5, 5) MSTEP(bq6, 6) MSTEP(bq7, 7)
        #undef MSTEP

        f32x4 am = (mt_own == 0) ? a0 : (mt_own == 1) ? a1 : (mt_own == 2) ? a2 : a3;
        float sv = (r_own == 0) ? am[0] : (r_own == 1) ? am[1] : (r_own == 2) ? am[2] : am[3];

        float act = fast_tanh(sv + e_cur);
        h_reg = alpha * h_reg + onema * act;
        hlds[CUR ^ 1][m] = (_Float16)h_reg;
        if (write_all)
            *((_Float16*)(bb + (size_t)t * HIDDEN) + m) = (_Float16)h_reg;
        barrier_lds_only();
        e_cur = e_n1;
        e_n1 = e_n2;
    };

    for (int t = t0; t < tend; t += 2) {
        step(std::integral_constant<int, 0>{}, t);
        step(std::integral_constant<int, 1>{}, t + 1);
    }
    h_carry[b * 256 + m] = h_reg;
}

// ---------------- ext GEMM: 2 batches x TBLK tiles, weights loaded once (r19) ----------------
__device__ __forceinline__ void gemm_chunk4(
    char* smem, float* buf, const _Float16* __restrict__ Wp,
    const float* __restrict__ bias, int gl, int c)
{
    constexpr int KT = 8, ROWB = 512;
    char* alds = smem;   // 32 rows * 512B = 16 KB
    const int tid = threadIdx.x;
    const int wave = tid >> 6, lane = tid & 63;
    const int bl = lane & 15, q = lane >> 4;

    f16x8 bfrag[4][KT];
    float bv[4];
    #pragma unroll
    for (int nt = 0; nt < 4; ++nt) {
        #pragma unroll
        for (int kt = 0; kt < KT; ++kt)
            bfrag[nt][kt] = __builtin_bit_cast(f16x8,
                *(const uint4*)((const char*)Wp + (size_t)(((wave * 4 + nt) * 8 + kt) * 64 + lane) * 16));
        bv[nt] = bias[wave * 64 + nt * 16 + bl];
    }

    for (int u = 0; u < 2 * TBLK; ++u) {
        int b = 2 * gl + (u >> 1);
        int half = u & 1;
        size_t m0 = (size_t)b * SEQ + (size_t)c * CHS + (size_t)half * 32;

        __syncthreads();
        #pragma unroll
        for (int it = 0; it < 4; ++it) {
            int idx = tid + it * 256;
            int row = idx >> 5, chunk = idx & 31;
            uint4 uu = *(const uint4*)((const char*)buf + (m0 + row) * 1024 + chunk * 16);
            *(uint4*)(alds + row * ROWB + ((chunk * 16) ^ ((row & 7) << 4))) = uu;
        }
        __syncthreads();

        f32x4 acc[2][4];
        #pragma unroll
        for (int mt = 0; mt < 2; ++mt)
            #pragma unroll
            for (int nt = 0; nt < 4; ++nt) acc[mt][nt] = (f32x4){0.f, 0.f, 0.f, 0.f};
        #pragma unroll
        for (int kt = 0; kt < KT; ++kt) {
            int inner = kt * 64 + q * 16;
            f16x8 a0 = __builtin_bit_cast(f16x8,
                *(const uint4*)(alds + (0 * 16 + bl) * ROWB + (inner ^ ((bl & 7) << 4))));
            f16x8 a1 = __builtin_bit_cast(f16x8,
                *(const uint4*)(alds + (1 * 16 + bl) * ROWB + (inner ^ ((bl & 7) << 4))));
            #pragma unroll
            for (int nt = 0; nt < 4; ++nt) {
                acc[0][nt] = __builtin_amdgcn_mfma_f32_16x16x32_f16(a0, bfrag[nt][kt], acc[0][nt], 0, 0, 0);
                acc[1][nt] = __builtin_amdgcn_mfma_f32_16x16x32_f16(a1, bfrag[nt][kt], acc[1][nt], 0, 0, 0);
            }
        }
        #pragma unroll
        for (int mt = 0; mt < 2; ++mt)
            #pragma unroll
            for (int nt = 0; nt < 4; ++nt) {
                int col = wave * 64 + nt * 16 + bl;
                #pragma unroll
                for (int r = 0; r < 4; ++r)
                    buf[(m0 + mt * 16 + q * 4 + r) * 256 + col] = acc[mt][nt][r] + bv[nt];
            }
    }
}

// ---------------- gemm0 chunk: ext0 = x @ Wf.T + bf for one (batch, chunk) = 64 rows ----------------
__device__ __forceinline__ void gemm0_chunk(
    char* smem, const float* __restrict__ x, const float* __restrict__ Wf,
    const float* __restrict__ bf, float* __restrict__ buf, int gl, int c)
{
    constexpr int KD = 128, KT = 4, ROWB = 256;
    char* alds = smem;   // 32 rows * 256B = 8 KB
    const int tid = threadIdx.x;
    const int wave = tid >> 6, lane = tid & 63;
    const int bl = lane & 15, q = lane >> 4;

    f16x8 bfrag[4][KT];
    float bv[4];
    #pragma unroll
    for (int nt = 0; nt < 4; ++nt) {
        int n = wave * 64 + nt * 16 + bl;
        const float* wr = Wf + (size_t)n * KD;
        #pragma unroll
        for (int kt = 0; kt < KT; ++kt) {
            const float4* wp = (const float4*)(wr + kt * 32 + q * 8);
            float4 u0 = wp[0], u1 = wp[1];
            uint4 u = { pkrtz(u0.x, u0.y), pkrtz(u0.z, u0.w),
                        pkrtz(u1.x, u1.y), pkrtz(u1.z, u1.w) };
            bfrag[nt][kt] = __builtin_bit_cast(f16x8, u);
        }
        bv[nt] = bf[n];
    }

    for (int half = 0; half < 2; ++half) {
        size_t m0 = (size_t)gl * SEQ + (size_t)c * CHS + (size_t)half * 32;
        const float* Asrc = x + m0 * KD;

        __syncthreads();
        #pragma unroll
        for (int it = 0; it < 2; ++it) {
            int idx = tid + it * 256;
            int row = idx >> 4, chunk = idx & 15;
            const float4* sp = (const float4*)(Asrc + (size_t)row * KD + chunk * 8);
            float4 f0 = sp[0], f1 = sp[1];
            uint4 u = { pkrtz(f0.x, f0.y), pkrtz(f0.z, f0.w),
                        pkrtz(f1.x, f1.y), pkrtz(f1.z, f1.w) };
            *(uint4*)(alds + row * ROWB + ((chunk * 16) ^ ((row & 7) << 4))) = u;
        }
        __syncthreads();

        f32x4 acc[2][4];
        #pragma unroll
        for (int mt = 0; mt < 2; ++mt)
            #pragma unroll
            for (int nt = 0; nt < 4; ++nt) acc[mt][nt] = (f32x4){0.f, 0.f, 0.f, 0.f};
        #pragma unroll
        for (int kt = 0; kt < KT; ++kt) {
            int inner = kt * 64 + q * 16;
            f16x8 a0 = __builtin_bit_cast(f16x8,
                *(const uint4*)(alds + (0 * 16 + bl) * ROWB + (inner ^ ((bl & 7) << 4))));
            f16x8 a1 = __builtin_bit_cast(f16x8,
                *(const uint4*)(alds + (1 * 16 + bl) * ROWB + (inner ^ ((bl & 7) << 4))));
            #pragma unroll
            for (int nt = 0; nt < 4; ++nt) {
                acc[0][nt] = __builtin_amdgcn_mfma_f32_16x16x32_f16(a0, bfrag[nt][kt], acc[0][nt], 0, 0, 0);
                acc[1][nt] = __builtin_amdgcn_mfma_f32_16x16x32_f16(a1, bfrag[nt][kt], acc[1][nt], 0, 0, 0);
            }
        }
        #pragma unroll
        for (int mt = 0; mt < 2; ++mt)
            #pragma unroll
            for (int nt = 0; nt < 4; ++nt) {
                int col = wave * 64 + nt * 16 + bl;
                #pragma unroll
                for (int r = 0; r < 4; ++r)
                    buf[(m0 + mt * 16 + q * 4 + r) * 256 + col] = acc[mt][nt][r] + bv[nt];
            }
    }
}

// ---------------- stage megakernel: 256 blocks = 1/CU (gemm0 folded into gemm role) ----------------
// [0,64): scanL0(c=s-1); [64,128): scanL1(c=s-3); [128,192): scanL2(c=s-5);
// [192,256): gemm role — ALL do gemm0(batch=blk-192, c=s), then
//            [192,224): gemm1(gl, c=s-2); [224,256): gemm2(gl, c=s-4).
__global__ __launch_bounds__(256, 1) void stage_kernel(
    int stage, float* buf, const float* __restrict__ x,
    const _Float16* __restrict__ wpk,   // [5][65536] packed: Wrec0,Wrec1,Wrec2,Win1,Win2
    const float* __restrict__ Wf, const float* __restrict__ bf,
    const float* __restrict__ bias,  const float* __restrict__ alphas,
    float* __restrict__ h_carry)
{
    __shared__ alignas(16) char smem[16384];
    int blk = blockIdx.x;
    if (blk < 192) {
        int layer = blk >> 6;
        int c = stage - 1 - 2 * layer;
        if (c < 0 || c >= CCH) return;
        scan_chunk(smem, buf, wpk + (size_t)layer * 65536, alphas + layer * 64,
                   h_carry + (size_t)layer * 16384, blk & 63, c, layer < 2);
    } else {
        int g = blk - 192;   // 0..63
        // sub-role A: gemm0 for batch g at chunk c = stage
        if (stage < CCH)
            gemm0_chunk(smem, x, Wf, bf, buf, g, stage);
        // sub-role B: ext gemm (which = g>>5) for batch pair gl = g&31
        int which = g >> 5;
        int gl = g & 31;
        int c = stage - 2 - 2 * which;
        if (c >= 0 && c < CCH)
            gemm_chunk4(smem, buf, wpk + (size_t)(3 + which) * 65536, bias + (which + 1) * 256, gl, c);
    }
}

// ---------------- final projection from h_carry[2] ----------------
__global__ __launch_bounds__(256) void outproj_kernel(
    const float* __restrict__ h_carry, const float* __restrict__ ow, const float* __restrict__ ob,
    float* __restrict__ out)
{
    __shared__ float h_l[256];
    __shared__ float p_lds[4][64];
    int b = blockIdx.x;
    int tid = threadIdx.x;
    h_l[tid] = h_carry[b * 256 + tid];
    __syncthreads();
    int o = tid & 63, qq = tid >> 6;
    float s = 0.f;
    const float4* wp = (const float4*)(ow + o * 256 + qq * 64);
    const float4* hp = (const float4*)(h_l + qq * 64);
    #pragma unroll
    for (int m = 0; m < 16; ++m) {
        float4 wv = wp[m]; float4 hv = hp[m];
        s = fmaf(wv.x, hv.x, s); s = fmaf(wv.y, hv.y, s);
        s = fmaf(wv.z, hv.z, s); s = fmaf(wv.w, hv.w, s);
    }
    p_lds[qq][o] = s;
    __syncthreads();
    if (tid < 64)
        out[b * 64 + tid] = p_lds[0][tid] + p_lds[1][tid] + p_lds[2][tid] + p_lds[3][tid] + ob[tid];
}

extern "C" void kernel_launch(void* const* d_in, const int* in_sizes, int n_in,
                              void* d_out, int out_size, void* d_ws, size_t ws_size,
                              hipStream_t stream)
{
    const float* x     = (const float*)d_in[0];
    const float* cw1   = (const float*)d_in[1];
    const float* cb1   = (const float*)d_in[2];
    const float* cw2   = (const float*)d_in[3];
    const float* cb2   = (const float*)d_in[4];
    const float* pw    = (const float*)d_in[5];
    const float* pb    = (const float*)d_in[6];
    const float* W_rec = (const float*)d_in[7];
    const float* W_in  = (const float*)d_in[8];
    const float* bias  = (const float*)d_in[9];
    const float* tau_b = (const float*)d_in[10];
    const float* tmw   = (const float*)d_in[11];
    const float* tmb   = (const float*)d_in[12];
    const float* ow    = (const float*)d_in[13];
    const float* ob    = (const float*)d_in[14];
    float* out = (float*)d_out;

    char* ws = (char*)d_ws;
    float*     alphas  = (float*)ws;                   // 192 f
    float*     h_carry = (float*)(ws + 1024);          // [3][64][256] f
    float*     bf      = (float*)(ws + 197632);        // 256 f
    float*     Wf      = (float*)(ws + 198656);        // 256*128 f
    _Float16*  wpk     = (_Float16*)(ws + 329728);     // [5][65536] f16
    float*     buf     = (float*)(ws + 1048576);       // [64][2048][256] f32 = 134.2MB

    prep_kernel<<<64, 1024, 0, stream>>>(x, cw1, cb1, cw2, cb2, tau_b, tmw, tmb, alphas, h_carry);
    wf_kernel<<<256, 128, 0, stream>>>(W_in, pw, pb, bias, Wf, bf);

    wpack_kernel<<<128, 64, 0, stream>>>(W_rec,          wpk);
    wpack_kernel<<<128, 64, 0, stream>>>(W_rec + 65536,  wpk + 65536);
    wpack_kernel<<<128, 64, 0, stream>>>(W_rec + 131072, wpk + 2 * 65536);
    wpack_kernel<<<128, 64, 0, stream>>>(W_in + 65536,   wpk + 3 * 65536);
    wpack_kernel<<<128, 64, 0, stream>>>(W_in + 131072,  wpk + 4 * 65536);

    // fully-pipelined: gemm0 + 3 scans + 2 ext-gemms, deps ride launch order; 1 block/CU
    for (int s = 0; s < CCH + 6; ++s)
        stage_kernel<<<256, 256, 0, stream>>>(s, buf, x, wpk, Wf, bf, bias, alphas, h_carry);

    outproj_kernel<<<64, 256, 0, stream>>>(h_carry + 2 * 16384, ow, ob, out);
}